// Round 11
// baseline (573.287 us; speedup 1.0000x reference)
//
#include <hip/hip_runtime.h>
#include <math.h>

// ---------------- problem constants (from reference) ----------------
constexpr int N0 = 262144, S1 = 32768, S2 = 4096, S3 = 512;
constexpr int E1 = 327680, E2 = 40960, E3 = 5120;
constexpr float NEG = 0.2f, BN_EPS = 1e-5f;

typedef __attribute__((ext_vector_type(8))) short short8;   // 8 bf16 (4 VGPRs)
typedef __attribute__((ext_vector_type(4))) float f32x4;    // MFMA acc

__device__ __forceinline__ float lrelu(float x) { return x > 0.f ? x : NEG * x; }

__device__ __forceinline__ unsigned short f2b(float f) {  // f32 -> bf16 RNE
    unsigned int u = __float_as_uint(f);
    return (unsigned short)((u + 0x7FFFu + ((u >> 16) & 1u)) >> 16);
}
__device__ __forceinline__ float b2f(unsigned short u) {
    return __uint_as_float(((unsigned int)u) << 16);
}
__device__ __forceinline__ void ld4(const float* __restrict__ p, float* o) {
    float4 v = *(const float4*)p;
    o[0] = v.x; o[1] = v.y; o[2] = v.z; o[3] = v.w;
}

// async global->LDS, 16B per lane; LDS dest = wave-uniform base + lane*16
__device__ __forceinline__ void gload_lds16(const unsigned short* g, unsigned short* l) {
    __builtin_amdgcn_global_load_lds(
        (const __attribute__((address_space(1))) unsigned int*)g,
        (__attribute__((address_space(3))) unsigned int*)l, 16, 0, 0);
}

// ==================== one-shot prep ====================
struct PrepArgs {
    const float* att[6]; const float* wf[6]; float* v[6];
    const float* csrc[6]; unsigned short* cdst[6];
    int* zptr; int zn4;
};

__global__ void prep_kernel(PrepArgs a)
{
    int b = blockIdx.x, t = threadIdx.x;
    if (b < 68) {
        int f, cb;
        if (b < 2)       { f = 0; cb = b; }
        else if (b < 4)  { f = 1; cb = b - 2; }
        else if (b < 20) { f = 2; cb = b - 4; }
        else if (b < 36) { f = 3; cb = b - 20; }
        else if (b < 52) { f = 4; cb = b - 36; }
        else             { f = 5; cb = b - 52; }
        int din = (f < 2) ? 128 : 1024;
        int idx = cb * 256 + t;
        int h = idx / din, k = idx - h * din;
        const float* ar = a.att[f] + h * 256;
        const float* wr = a.wf[f] + (size_t)(h * 256) * din + k;
        float acc = 0.f;
        for (int j = 0; j < 256; ++j) acc += ar[j] * wr[(size_t)j * din];
        a.v[f][idx] = acc;
    } else if (b < 124) {
        int c = b - 68, j, ob;
        if (c < 2)       { j = 0; ob = c; }
        else if (c < 4)  { j = 1; ob = c - 2; }
        else if (c < 20) { j = 2; ob = c - 4; }
        else if (c < 36) { j = 3; ob = c - 20; }
        else if (c < 40) { j = 4; ob = c - 36; }
        else             { j = 5; ob = c - 40; }
        long base = (long)ob * 65536;
        if (j < 5) {
            const float* src = a.csrc[j];
            unsigned short* dst = a.cdst[j];
            for (int it = 0; it < 64; ++it) {
                long e = base + (long)(it * 256 + t) * 4;
                float4 v = *(const float4*)(src + e);
                ushort4 u;
                u.x = f2b(v.x); u.y = f2b(v.y); u.z = f2b(v.z); u.w = f2b(v.w);
                *(ushort4*)(dst + e) = u;
            }
        } else {  // w3 repack: wp[row*4096 + h*1024 + k] = 0.25*w[(h*256+row)*1024+k]
            const float* src = a.csrc[5];
            unsigned short* dst = a.cdst[5];
            for (int it = 0; it < 64; ++it) {
                long e = base + (long)(it * 256 + t) * 4;
                int row = (int)(e >> 12);
                int hk = (int)(e & 4095);
                int h = hk >> 10, k = hk & 1023;
                float4 v = *(const float4*)(src + ((size_t)(h * 256 + row) << 10) + k);
                ushort4 u;
                u.x = f2b(0.25f * v.x); u.y = f2b(0.25f * v.y);
                u.z = f2b(0.25f * v.z); u.w = f2b(0.25f * v.w);
                *(ushort4*)(dst + e) = u;
            }
        }
    } else {
        int i = (b - 124) * 256 + t;
        if (i < a.zn4) ((int4*)a.zptr)[i] = make_int4(0, 0, 0, 0);
    }
}

// ==================== CSR build for ALL layers (input-only) ====================
struct CsrArgs {
    const int* edst[3]; const int* esrc[3];
    int* counts[3]; int* offsets[3]; int* cursor[3]; int* slist[3];
    int sizes[3];
};

__global__ void count_all(CsrArgs a)
{
    int id = blockIdx.x * 256 + threadIdx.x;
    int L, e;
    if (id < E1)           { L = 0; e = id; }
    else if (id < E1 + E2) { L = 1; e = id - E1; }
    else if (id < E1 + E2 + E3) { L = 2; e = id - E1 - E2; }
    else return;
    atomicAdd(&a.counts[L][a.edst[L][e]], 1);
}

__global__ void scan_all(CsrArgs a)
{
    __shared__ int lds[1024];
    int L = blockIdx.x;
    int size = a.sizes[L];
    const int* counts = a.counts[L];
    int* offsets = a.offsets[L];
    int* cursor = a.cursor[L];
    int t = threadIdx.x;
    int chunk = (size + 1023) >> 10;
    int begin = t * chunk;
    int end = begin + chunk; if (end > size) end = size;
    if (begin > size) begin = size;
    int s = 0;
    if ((chunk & 3) == 0) {
        for (int i = begin; i < end; i += 4) {
            int4 v = *(const int4*)(counts + i);
            s += v.x + v.y + v.z + v.w;
        }
    } else {
        for (int i = begin; i < end; ++i) s += counts[i];
    }
    lds[t] = s;
    __syncthreads();
    for (int d = 1; d < 1024; d <<= 1) {
        int v = (t >= d) ? lds[t - d] : 0;
        __syncthreads();
        lds[t] += v;
        __syncthreads();
    }
    int base = (t > 0) ? lds[t - 1] : 0;
    for (int i = begin; i < end; ++i) {
        offsets[i] = base; cursor[i] = base;
        base += counts[i];
    }
    if (t == 1023) offsets[size] = lds[1023];
}

__global__ void scatter_all(CsrArgs a)
{
    int id = blockIdx.x * 256 + threadIdx.x;
    int L, e;
    if (id < E1)           { L = 0; e = id; }
    else if (id < E1 + E2) { L = 1; e = id - E1; }
    else if (id < E1 + E2 + E3) { L = 2; e = id - E1 - E2; }
    else return;
    int p = atomicAdd(&a.cursor[L][a.edst[L][e]], 1);
    a.slist[L][p] = a.esrc[L][e];
}

// ==================== L1: fused f32->bf16 conv + al_src + al_dst ====================
__global__ void al128f_kernel(const float* __restrict__ x, const float* __restrict__ vs,
                              const float* __restrict__ vd, unsigned short* __restrict__ xb,
                              float* __restrict__ als, float* __restrict__ ald, int n, int ndst)
{
    int lane = threadIdx.x & 63;
    int wave = (blockIdx.x * 256 + threadIdx.x) >> 6;
    int nw = (gridDim.x * 256) >> 6;
    int j32 = lane & 31, half = lane >> 5;
    float vsr[4][4], vdr[4][4];
    #pragma unroll
    for (int h = 0; h < 4; ++h) {
        ld4(vs + h * 128 + j32 * 4, vsr[h]);
        ld4(vd + h * 128 + j32 * 4, vdr[h]);
    }
    for (long node = (long)wave * 2 + half; node < n; node += (long)nw * 2) {
        float4 xv = *(const float4*)(x + node * 128 + j32 * 4);
        ushort4 u;
        u.x = f2b(xv.x); u.y = f2b(xv.y); u.z = f2b(xv.z); u.w = f2b(xv.w);
        *(ushort4*)(xb + node * 128 + j32 * 4) = u;
        float xf[4] = { xv.x, xv.y, xv.z, xv.w };
        float a[4], bv[4];
        bool isd = node < ndst;
        #pragma unroll
        for (int h = 0; h < 4; ++h)
            a[h] = xf[0]*vsr[h][0] + xf[1]*vsr[h][1] + xf[2]*vsr[h][2] + xf[3]*vsr[h][3];
        if (isd) {
            #pragma unroll
            for (int h = 0; h < 4; ++h)
                bv[h] = xf[0]*vdr[h][0] + xf[1]*vdr[h][1] + xf[2]*vdr[h][2] + xf[3]*vdr[h][3];
        }
        #pragma unroll
        for (int off = 16; off > 0; off >>= 1) {
            #pragma unroll
            for (int h = 0; h < 4; ++h) a[h] += __shfl_xor(a[h], off);
            if (isd)
                #pragma unroll
                for (int h = 0; h < 4; ++h) bv[h] += __shfl_xor(bv[h], off);
        }
        if (j32 == 0) {
            *(float4*)(als + node * 4) = make_float4(a[0], a[1], a[2], a[3]);
            if (isd) *(float4*)(ald + node * 4) = make_float4(bv[0], bv[1], bv[2], bv[3]);
        }
    }
}

// ==================== fused BN+ELU apply + next-layer al_src ====================
// Writes normalized bf16 features AND computes als from the ROUNDED values
// (bit-identical to the prior two-kernel pipeline). State/lane: sc16+sh16+v64 = 96 f32.
__global__ void norm_al_kernel(const unsigned short* __restrict__ h,
                               const float* __restrict__ sum, const float* __restrict__ sq,
                               const float* __restrict__ gamma, const float* __restrict__ beta,
                               const float* __restrict__ vs,
                               unsigned short* __restrict__ xb, float* __restrict__ als,
                               int M, float invM)
{
    int lane = threadIdx.x & 63;
    int wave = (blockIdx.x * 256 + threadIdx.x) >> 6;
    int nwaves = (gridDim.x * 256) >> 6;
    float sc[16], sh[16], vr[4][16];
    #pragma unroll
    for (int it = 0; it < 2; ++it) {
        int c0 = it * 512 + lane * 8;
        #pragma unroll
        for (int g = 0; g < 2; ++g) {
            float4 sm = *(const float4*)(sum + c0 + g * 4);
            float4 qq = *(const float4*)(sq + c0 + g * 4);
            float4 gm = *(const float4*)(gamma + c0 + g * 4);
            float4 bt = *(const float4*)(beta + c0 + g * 4);
            int o = it * 8 + g * 4;
            float mu;
            mu = sm.x * invM; sc[o+0] = gm.x * rsqrtf(qq.x * invM - mu * mu + BN_EPS); sh[o+0] = bt.x - mu * sc[o+0];
            mu = sm.y * invM; sc[o+1] = gm.y * rsqrtf(qq.y * invM - mu * mu + BN_EPS); sh[o+1] = bt.y - mu * sc[o+1];
            mu = sm.z * invM; sc[o+2] = gm.z * rsqrtf(qq.z * invM - mu * mu + BN_EPS); sh[o+2] = bt.z - mu * sc[o+2];
            mu = sm.w * invM; sc[o+3] = gm.w * rsqrtf(qq.w * invM - mu * mu + BN_EPS); sh[o+3] = bt.w - mu * sc[o+3];
        }
    }
    #pragma unroll
    for (int hh = 0; hh < 4; ++hh)
        #pragma unroll
        for (int it = 0; it < 2; ++it) {
            ld4(vs + hh * 1024 + it * 512 + lane * 8,     &vr[hh][it * 8]);
            ld4(vs + hh * 1024 + it * 512 + lane * 8 + 4, &vr[hh][it * 8 + 4]);
        }
    for (long node = wave; node < M; node += nwaves) {
        const unsigned short* xr = h + node * 1024;
        float a[4] = {0.f, 0.f, 0.f, 0.f};
        #pragma unroll
        for (int it = 0; it < 2; ++it) {
            short8 u = *(const short8*)(xr + it * 512 + lane * 8);
            short8 o;
            #pragma unroll
            for (int j = 0; j < 8; ++j) {
                float v = b2f((unsigned short)u[j]) * sc[it * 8 + j] + sh[it * 8 + j];
                v = v > 0.f ? v : expm1f(v);
                unsigned short vb = f2b(v);
                o[j] = (short)vb;
                float xv = b2f(vb);
                #pragma unroll
                for (int hh = 0; hh < 4; ++hh) a[hh] += xv * vr[hh][it * 8 + j];
            }
            *(short8*)(xb + node * 1024 + it * 512 + lane * 8) = o;
        }
        #pragma unroll
        for (int off = 32; off > 0; off >>= 1)
            #pragma unroll
            for (int hh = 0; hh < 4; ++hh) a[hh] += __shfl_xor(a[hh], off);
        if (lane == 0) *(float4*)(als + node * 4) = make_float4(a[0], a[1], a[2], a[3]);
    }
}

// ==================== single-v al over a node prefix (dst logits) ====================
__global__ void al1024s_kernel(const unsigned short* __restrict__ xb, const float* __restrict__ v,
                               float* __restrict__ al, int n)
{
    int lane = threadIdx.x & 63;
    int wave = (blockIdx.x * 256 + threadIdx.x) >> 6;
    int nwaves = (gridDim.x * 256) >> 6;
    float vr[4][16];
    #pragma unroll
    for (int h = 0; h < 4; ++h)
        #pragma unroll
        for (int it = 0; it < 2; ++it) {
            ld4(v + h * 1024 + it * 512 + lane * 8,     &vr[h][it * 8]);
            ld4(v + h * 1024 + it * 512 + lane * 8 + 4, &vr[h][it * 8 + 4]);
        }
    for (long node = wave; node < n; node += nwaves) {
        const unsigned short* xr = xb + node * 1024;
        float a[4] = {0.f, 0.f, 0.f, 0.f};
        #pragma unroll
        for (int it = 0; it < 2; ++it) {
            short8 u = *(const short8*)(xr + it * 512 + lane * 8);
            #pragma unroll
            for (int j = 0; j < 8; ++j) {
                float xv = b2f((unsigned short)u[j]);
                #pragma unroll
                for (int h = 0; h < 4; ++h) a[h] += xv * vr[h][it * 8 + j];
            }
        }
        #pragma unroll
        for (int off = 32; off > 0; off >>= 1)
            #pragma unroll
            for (int h = 0; h < 4; ++h) a[h] += __shfl_xor(a[h], off);
        if (lane == 0) *(float4*)(al + node * 4) = make_float4(a[0], a[1], a[2], a[3]);
    }
}

// ==================== wave-parallel softmax stats + per-slot alpha ====================
__global__ void mdnw_kernel(const float* __restrict__ als, const float* __restrict__ ald,
                            const int* __restrict__ offsets, const int* __restrict__ slist,
                            int size, float* __restrict__ aself, float* __restrict__ walpha)
{
    int d = blockIdx.x * 4 + (threadIdx.x >> 6);
    if (d >= size) return;
    int lane = threadIdx.x & 63;
    float ad[4], sl[4], q[4];
    ld4(ald + 4 * (size_t)d, ad);
    ld4(als + 4 * (size_t)d, q);
    #pragma unroll
    for (int h = 0; h < 4; ++h) sl[h] = lrelu(q[h] + ad[h]);
    int beg = offsets[d], deg = offsets[d + 1] - beg;
    float m[4] = { sl[0], sl[1], sl[2], sl[3] };
    for (int p = lane; p < deg; p += 64) {
        int s = slist[beg + p];
        ld4(als + 4 * (size_t)s, q);
        #pragma unroll
        for (int h = 0; h < 4; ++h) m[h] = fmaxf(m[h], lrelu(q[h] + ad[h]));
    }
    #pragma unroll
    for (int off = 32; off > 0; off >>= 1)
        #pragma unroll
        for (int h = 0; h < 4; ++h) m[h] = fmaxf(m[h], __shfl_xor(m[h], off));
    float dn[4] = {0.f, 0.f, 0.f, 0.f};
    for (int p = lane; p < deg; p += 64) {
        int s = slist[beg + p];
        ld4(als + 4 * (size_t)s, q);
        #pragma unroll
        for (int h = 0; h < 4; ++h) dn[h] += expf(lrelu(q[h] + ad[h]) - m[h]);
    }
    #pragma unroll
    for (int off = 32; off > 0; off >>= 1)
        #pragma unroll
        for (int h = 0; h < 4; ++h) dn[h] += __shfl_xor(dn[h], off);
    float r[4];
    #pragma unroll
    for (int h = 0; h < 4; ++h)
        r[h] = 1.f / (dn[h] + expf(sl[h] - m[h]) + 1e-16f);
    if (lane == 0) {
        float4 w;
        w.x = expf(sl[0] - m[0]) * r[0];
        w.y = expf(sl[1] - m[1]) * r[1];
        w.z = expf(sl[2] - m[2]) * r[2];
        w.w = expf(sl[3] - m[3]) * r[3];
        *(float4*)(aself + 4 * (size_t)d) = w;
    }
    for (int p = lane; p < deg; p += 64) {
        int s = slist[beg + p];
        ld4(als + 4 * (size_t)s, q);
        float4 w;
        w.x = expf(lrelu(q[0] + ad[0]) - m[0]) * r[0];
        w.y = expf(lrelu(q[1] + ad[1]) - m[1]) * r[1];
        w.z = expf(lrelu(q[2] + ad[2]) - m[2]) * r[2];
        w.w = expf(lrelu(q[3] + ad[3]) - m[3]) * r[3];
        *(float4*)(walpha + 4 * (size_t)(beg + p)) = w;
    }
}

// ==================== aggregation (slot-indexed alpha, direct src ids) ====================
// 4 dsts per 256-thread block (one wave each)
__global__ void agg128_kernel(const unsigned short* __restrict__ xb, const float* __restrict__ walpha,
                              const float* __restrict__ aself,
                              const int* __restrict__ offsets, const int* __restrict__ slist,
                              int size, unsigned short* __restrict__ aggb)
{
    int d = blockIdx.x * 4 + (threadIdx.x >> 6);
    if (d >= size) return;
    int lane = threadIdx.x & 63;
    int beg = offsets[d], end = offsets[d + 1];
    float w[4], acc[4][2];
    ld4(aself + 4 * (size_t)d, w);
    {
        unsigned int u = *(const unsigned int*)(xb + (size_t)d * 128 + lane * 2);
        float x0 = b2f((unsigned short)(u & 0xFFFF)), x1 = b2f((unsigned short)(u >> 16));
        #pragma unroll
        for (int h = 0; h < 4; ++h) { acc[h][0] = w[h] * x0; acc[h][1] = w[h] * x1; }
    }
    for (int p = beg; p < end; ++p) {
        int s = slist[p];
        ld4(walpha + 4 * (size_t)p, w);
        unsigned int u = *(const unsigned int*)(xb + (size_t)s * 128 + lane * 2);
        float x0 = b2f((unsigned short)(u & 0xFFFF)), x1 = b2f((unsigned short)(u >> 16));
        #pragma unroll
        for (int h = 0; h < 4; ++h) { acc[h][0] += w[h] * x0; acc[h][1] += w[h] * x1; }
    }
    unsigned int* og = (unsigned int*)(aggb + (size_t)d * 512);
    #pragma unroll
    for (int h = 0; h < 4; ++h)
        og[h * 64 + lane] = (unsigned int)f2b(acc[h][0]) | ((unsigned int)f2b(acc[h][1]) << 16);
}

__global__ void agg1024_kernel(const unsigned short* __restrict__ xb, const float* __restrict__ walpha,
                               const float* __restrict__ aself,
                               const int* __restrict__ offsets, const int* __restrict__ slist,
                               unsigned short* __restrict__ aggb)
{
    int d = blockIdx.x, t = threadIdx.x;
    int beg = offsets[d], end = offsets[d + 1];
    float w[4], acc[4][4];
    ld4(aself + 4 * (size_t)d, w);
    {
        ushort4 u = *(const ushort4*)(xb + (size_t)d * 1024 + t * 4);
        float xv[4] = { b2f(u.x), b2f(u.y), b2f(u.z), b2f(u.w) };
        #pragma unroll
        for (int h = 0; h < 4; ++h)
            #pragma unroll
            for (int j = 0; j < 4; ++j) acc[h][j] = w[h] * xv[j];
    }
    for (int p = beg; p < end; ++p) {
        int s = slist[p];
        ld4(walpha + 4 * (size_t)p, w);
        ushort4 u = *(const ushort4*)(xb + (size_t)s * 1024 + t * 4);
        float xv[4] = { b2f(u.x), b2f(u.y), b2f(u.z), b2f(u.w) };
        #pragma unroll
        for (int h = 0; h < 4; ++h)
            #pragma unroll
            for (int j = 0; j < 4; ++j) acc[h][j] += w[h] * xv[j];
    }
    unsigned short* og = aggb + (size_t)d * 4096;
    #pragma unroll
    for (int h = 0; h < 4; ++h) {
        ushort4 u;
        u.x = f2b(acc[h][0]); u.y = f2b(acc[h][1]);
        u.z = f2b(acc[h][2]); u.w = f2b(acc[h][3]);
        *(ushort4*)(og + h * 1024 + t * 4) = u;
    }
}

// ==================== fused dual-phase bf16 MFMA GEMM + BN stats (L1/L2) ====================
#define SWZ(r, c) ((((c) ^ (((r) >> 1) & 3)) << 3))

template<int BM, int BN>
__global__ __launch_bounds__(256) void gemm2_kernel(
    const unsigned short* __restrict__ A1, int lda1, const unsigned short* __restrict__ W1, int K1,
    const unsigned short* __restrict__ A2, int lda2, const unsigned short* __restrict__ W2, int K2,
    int hs2, int cph2,
    unsigned short* __restrict__ C, int N,
    float* __restrict__ bnsum, float* __restrict__ bnsq)
{
    constexpr int WM = BM / 2, WN = BN / 2;
    constexpr int TM = WM / 16, TN = WN / 16;
    constexpr int APASS = (BM * 4) / 256, BPASS = (BN * 4) / 256;
    __shared__ __align__(16) unsigned short As[BM * 32];
    __shared__ __align__(16) unsigned short Bs[BN * 32];
    __shared__ float sbn[2 * BN];
    int tid = threadIdx.x;
    int gx = gridDim.x;
    int nwg = gx * gridDim.y;
    int bid = blockIdx.y * gx + blockIdx.x;
    int cpx = nwg >> 3;
    int swz = (bid & 7) * cpx + (bid >> 3);
    int n0 = (swz % gx) * BN, m0 = (swz / gx) * BM;
    int l = tid & 63, l16 = l & 15, kq = l >> 4;
    int wid = tid >> 6, wr = wid >> 1, wc = wid & 1;

    f32x4 acc[TM][TN];
    #pragma unroll
    for (int mi = 0; mi < TM; ++mi)
        #pragma unroll
        for (int ni = 0; ni < TN; ++ni) acc[mi][ni] = (f32x4){0.f, 0.f, 0.f, 0.f};

    #pragma unroll
    for (int ph = 0; ph < 2; ++ph) {
        const unsigned short* Ap = ph ? A2 + (size_t)m0 * lda2 + (cph2 ? (size_t)(n0 / cph2) * hs2 : 0)
                                      : A1 + (size_t)m0 * lda1;
        int lda = ph ? lda2 : lda1;
        const unsigned short* Wp = ph ? W2 + (size_t)n0 * K2 : W1 + (size_t)n0 * K1;
        int ldw = ph ? K2 : K1;
        int K = ph ? K2 : K1;
        for (int k0 = 0; k0 < K; k0 += 32) {
            #pragma unroll
            for (int ps = 0; ps < APASS; ++ps) {
                int sbase = ps * 256 + wid * 64;
                int s = sbase + l;
                int r = s >> 2, cc = s & 3;
                gload_lds16(Ap + (size_t)r * lda + k0 + ((cc ^ ((r >> 1) & 3)) << 3),
                            &As[(size_t)sbase * 8]);
            }
            #pragma unroll
            for (int ps = 0; ps < BPASS; ++ps) {
                int sbase = ps * 256 + wid * 64;
                int s = sbase + l;
                int r = s >> 2, cc = s & 3;
                gload_lds16(Wp + (size_t)r * ldw + k0 + ((cc ^ ((r >> 1) & 3)) << 3),
                            &Bs[(size_t)sbase * 8]);
            }
            __syncthreads();
            short8 af[TM], bfr[TN];
            #pragma unroll
            for (int mi = 0; mi < TM; ++mi) {
                int r = wr * WM + mi * 16 + l16;
                af[mi] = *(const short8*)&As[r * 32 + SWZ(r, kq)];
            }
            #pragma unroll
            for (int ni = 0; ni < TN; ++ni) {
                int r = wc * WN + ni * 16 + l16;
                bfr[ni] = *(const short8*)&Bs[r * 32 + SWZ(r, kq)];
            }
            #pragma unroll
            for (int mi = 0; mi < TM; ++mi)
                #pragma unroll
                for (int ni = 0; ni < TN; ++ni)
                    acc[mi][ni] = __builtin_amdgcn_mfma_f32_16x16x32_bf16(
                        af[mi], bfr[ni], acc[mi][ni], 0, 0, 0);
            __syncthreads();
        }
    }

    if (tid < 2 * BN) sbn[tid] = 0.f;
    __syncthreads();

    #pragma unroll
    for (int ni = 0; ni < TN; ++ni) {
        int col = wc * WN + ni * 16 + l16;
        float s = 0.f, q = 0.f;
        #pragma unroll
        for (int mi = 0; mi < TM; ++mi) {
            int rowb = wr * WM + mi * 16 + (kq << 2);
            #pragma unroll
            for (int r = 0; r < 4; ++r) {
                float v = acc[mi][ni][r];
                C[(size_t)(m0 + rowb + r) * N + n0 + col] = f2b(v);
                s += v; q += v * v;
            }
        }
        atomicAdd(&sbn[col * 2 + 0], s);
        atomicAdd(&sbn[col * 2 + 1], q);
    }
    __syncthreads();
    if (tid < BN) {
        atomicAdd(&bnsum[n0 + tid], sbn[tid * 2 + 0]);
        atomicAdd(&bnsq[n0 + tid], sbn[tid * 2 + 1]);
    }
}

// ==================== L3: split-K GEMM -> Cpart[z][512][256] (deterministic) ====================
__global__ __launch_bounds__(256) void gemm3_splitk(
    const unsigned short* __restrict__ A1, const unsigned short* __restrict__ W1,
    const unsigned short* __restrict__ A2, const unsigned short* __restrict__ W2,
    float* __restrict__ Cpart)
{
    constexpr int BM = 64, BN = 64, WM = 32, WN = 32, TM = 2, TN = 2;
    __shared__ __align__(16) unsigned short As[BM * 32];
    __shared__ __align__(16) unsigned short Bs[BN * 32];
    int tid = threadIdx.x;
    int n0 = blockIdx.x * BN, m0 = blockIdx.y * BM;
    int z = blockIdx.z;
    int ph = (z >= 2);
    int ks = ph ? (z - 2) * 512 : z * 512;
    const unsigned short* Ap = ph ? A2 + (size_t)m0 * 4096 : A1 + (size_t)m0 * 1024;
    const unsigned short* Wp = ph ? W2 + (size_t)n0 * 4096 : W1 + (size_t)n0 * 1024;
    int lda = ph ? 4096 : 1024;
    int l = tid & 63, l16 = l & 15, kq = l >> 4;
    int wid = tid >> 6, wr = wid >> 1, wc = wid & 1;

    f32x4 acc[TM][TN];
    #pragma unroll
    for (int mi = 0; mi < TM; ++mi)
        #pragma unroll
        for (int ni = 0; ni < TN; ++ni) acc[mi][ni] = (f32x4){0.f, 0.f, 0.f, 0.f};

    for (int k0 = ks; k0 < ks + 512; k0 += 32) {
        {
            int sbase = wid * 64;
            int s = sbase + l;
            int r = s >> 2, cc = s & 3;
            gload_lds16(Ap + (size_t)r * lda + k0 + ((cc ^ ((r >> 1) & 3)) << 3),
                        &As[(size_t)sbase * 8]);
            gload_lds16(Wp + (size_t)r * lda + k0 + ((cc ^ ((r >> 1) & 3)) << 3),
                        &Bs[(size_t)sbase * 8]);
        }
        __syncthreads();
        short8 af[TM], bfr[TN];
        #pragma unroll
        for (int mi = 0; mi < TM; ++mi) {
            int r = wr * WM + mi * 16 + l16;
            af[mi] = *(const short8*)&As[r * 32 + SWZ(r, kq)];
        }
        #pragma unroll
        for (int ni = 0; ni < TN; ++ni) {
            int r = wc * WN + ni * 16 + l16;
            bfr[ni] = *(const short8*)&Bs[r * 32 + SWZ(r, kq)];
        }
        #pragma unroll
        for (int mi = 0; mi < TM; ++mi)
            #pragma unroll
            for (int ni = 0; ni < TN; ++ni)
                acc[mi][ni] = __builtin_amdgcn_mfma_f32_16x16x32_bf16(
                    af[mi], bfr[ni], acc[mi][ni], 0, 0, 0);
        __syncthreads();
    }

    float* Cz = Cpart + (size_t)z * S3 * 256;
    #pragma unroll
    for (int ni = 0; ni < TN; ++ni) {
        int col = wc * WN + ni * 16 + l16;
        #pragma unroll
        for (int mi = 0; mi < TM; ++mi) {
            int rowb = wr * WM + mi * 16 + (kq << 2);
            #pragma unroll
            for (int r = 0; r < 4; ++r)
                Cz[(size_t)(m0 + rowb + r) * 256 + n0 + col] = acc[mi][ni][r];
        }
    }
}

// reduce Cpart over z -> hb32, accumulate BN column stats
__global__ void bnstat3_kernel(const float* __restrict__ Cpart, float* __restrict__ hb32,
                               float* __restrict__ bnsum, float* __restrict__ bnsq)
{
    int c = threadIdx.x;
    int r0 = blockIdx.x * 64;
    float s = 0.f, q = 0.f;
    for (int r = r0; r < r0 + 64; ++r) {
        float v = 0.f;
        #pragma unroll
        for (int z = 0; z < 10; ++z)
            v += Cpart[((size_t)z * S3 + r) * 256 + c];
        hb32[(size_t)r * 256 + c] = v;
        s += v; q += v * v;
    }
    atomicAdd(&bnsum[c], s);
    atomicAdd(&bnsq[c], q);
}

// ==================== final BN+ELU (f32 in/out) ====================
__global__ void norm_elu_ff(const float* __restrict__ h,
                            const float* __restrict__ sum, const float* __restrict__ sq,
                            const float* __restrict__ gamma, const float* __restrict__ beta,
                            float* __restrict__ out, int N, float invM, long total)
{
    long i = ((long)blockIdx.x * 256 + threadIdx.x) * 4;
    if (i >= total) return;
    int c = (int)(i % N);
    float4 sm = *(const float4*)(sum + c);
    float4 qq = *(const float4*)(sq + c);
    float4 gm = *(const float4*)(gamma + c);
    float4 bt = *(const float4*)(beta + c);
    float mu0 = sm.x * invM, mu1 = sm.y * invM, mu2 = sm.z * invM, mu3 = sm.w * invM;
    float sc0 = gm.x * rsqrtf(qq.x * invM - mu0 * mu0 + BN_EPS);
    float sc1 = gm.y * rsqrtf(qq.y * invM - mu1 * mu1 + BN_EPS);
    float sc2 = gm.z * rsqrtf(qq.z * invM - mu2 * mu2 + BN_EPS);
    float sc3 = gm.w * rsqrtf(qq.w * invM - mu3 * mu3 + BN_EPS);
    float4 hv = *(const float4*)(h + i);
    float4 o;
    o.x = hv.x * sc0 + (bt.x - mu0 * sc0);
    o.y = hv.y * sc1 + (bt.y - mu1 * sc1);
    o.z = hv.z * sc2 + (bt.z - mu2 * sc2);
    o.w = hv.w * sc3 + (bt.w - mu3 * sc3);
    o.x = o.x > 0.f ? o.x : expm1f(o.x);
    o.y = o.y > 0.f ? o.y : expm1f(o.y);
    o.z = o.z > 0.f ? o.z : expm1f(o.z);
    o.w = o.w > 0.f ? o.w : expm1f(o.w);
    *(float4*)(out + i) = o;
}

// =====================================================================
extern "C" void kernel_launch(void* const* d_in, const int* in_sizes, int n_in,
                              void* d_out, int out_size, void* d_ws, size_t ws_size,
                              hipStream_t stream)
{
    const float* x = (const float*)d_in[0];
    auto P = [&](int layer, int slot) -> const float* {
        return (const float*)d_in[1 + (layer - 1) * 9 + slot];
    };
    const int* edge_src[3] = { (const int*)d_in[28], (const int*)d_in[30], (const int*)d_in[32] };
    const int* edge_dst[3] = { (const int*)d_in[29], (const int*)d_in[31], (const int*)d_in[33] };

    // -------- workspace carve --------
    char* wsb = (char*)d_ws;
    size_t off = 0;
    auto alloc = [&](size_t bytes) -> void* {
        void* p = wsb + off;
        off = (off + bytes + 255) & ~(size_t)255;
        return p;
    };
    unsigned short* xb0   = (unsigned short*)alloc((size_t)N0 * 128 * 2);
    unsigned short* x1b   = (unsigned short*)alloc((size_t)S1 * 1024 * 2);
    unsigned short* x2b   = (unsigned short*)alloc((size_t)S2 * 1024 * 2);
    unsigned short* hb    = (unsigned short*)alloc((size_t)S1 * 1024 * 2);
    unsigned short* aggb  = (unsigned short*)alloc((size_t)S2 * 4096 * 2);
    unsigned short* wskipb[3] = {
        (unsigned short*)alloc(131072 * 2),
        (unsigned short*)alloc(1048576 * 2),
        (unsigned short*)alloc(262144 * 2) };
    unsigned short* wsrcb[3] = {
        (unsigned short*)alloc(131072 * 2),
        (unsigned short*)alloc(1048576 * 2),
        (unsigned short*)alloc(1048576 * 2) };
    float* vbuf[6];
    vbuf[0] = (float*)alloc(512 * 4);
    vbuf[1] = (float*)alloc(512 * 4);
    vbuf[2] = (float*)alloc(4096 * 4);
    vbuf[3] = (float*)alloc(4096 * 4);
    vbuf[4] = (float*)alloc(4096 * 4);
    vbuf[5] = (float*)alloc(4096 * 4);
    float* als     = (float*)alloc((size_t)N0 * 4 * 4);
    float* ald     = (float*)alloc((size_t)S1 * 4 * 4);
    float* aself   = (float*)alloc((size_t)S1 * 4 * 4);
    float* walpha  = (float*)alloc((size_t)E1 * 4 * 4);
    float* Cpart   = (float*)alloc((size_t)10 * S3 * 256 * 4);
    float* hb32    = (float*)alloc((size_t)S3 * 256 * 4);
    int* offsets3[3] = { (int*)alloc((S1 + 1) * 4), (int*)alloc((S2 + 1) * 4), (int*)alloc((S3 + 1) * 4) };
    int* cursor3 [3] = { (int*)alloc(S1 * 4), (int*)alloc(S2 * 4), (int*)alloc(S3 * 4) };
    int* slist3  [3] = { (int*)alloc(E1 * 4), (int*)alloc(E2 * 4), (int*)alloc(E3 * 4) };
    int zn = S1 + S2 + S3 + 6 * 1024;
    int* zreg = (int*)alloc((size_t)zn * 4);
    int* counts[3] = { zreg, zreg + S1, zreg + S1 + S2 };
    float* bnsum[3] = { (float*)(zreg + S1 + S2 + S3),
                        (float*)(zreg + S1 + S2 + S3 + 2048),
                        (float*)(zreg + S1 + S2 + S3 + 4096) };
    float* bnsq[3]  = { bnsum[0] + 1024, bnsum[1] + 1024, bnsum[2] + 1024 };

    // -------- one-shot prep: folds + weight bf16 + zeroing --------
    PrepArgs pa;
    for (int L = 0; L < 3; ++L) {
        pa.att[2 * L]     = P(L + 1, 2); pa.wf[2 * L]     = P(L + 1, 0); pa.v[2 * L]     = vbuf[2 * L];
        pa.att[2 * L + 1] = P(L + 1, 3); pa.wf[2 * L + 1] = P(L + 1, 1); pa.v[2 * L + 1] = vbuf[2 * L + 1];
    }
    pa.csrc[0] = P(1, 5); pa.cdst[0] = wskipb[0];
    pa.csrc[1] = P(1, 0); pa.cdst[1] = wsrcb[0];
    pa.csrc[2] = P(2, 5); pa.cdst[2] = wskipb[1];
    pa.csrc[3] = P(2, 0); pa.cdst[3] = wsrcb[1];
    pa.csrc[4] = P(3, 5); pa.cdst[4] = wskipb[2];
    pa.csrc[5] = P(3, 0); pa.cdst[5] = wsrcb[2];
    pa.zptr = zreg; pa.zn4 = zn / 4;
    prep_kernel<<<167, 256, 0, stream>>>(pa);

    // -------- CSR build for all layers --------
    CsrArgs ca;
    for (int L = 0; L < 3; ++L) {
        ca.edst[L] = edge_dst[L]; ca.esrc[L] = edge_src[L];
        ca.counts[L] = counts[L]; ca.offsets[L] = offsets3[L];
        ca.cursor[L] = cursor3[L]; ca.slist[L] = slist3[L];
    }
    ca.sizes[0] = S1; ca.sizes[1] = S2; ca.sizes[2] = S3;
    count_all<<<(E1 + E2 + E3) / 256, 256, 0, stream>>>(ca);
    scan_all<<<3, 1024, 0, stream>>>(ca);
    scatter_all<<<(E1 + E2 + E3) / 256, 256, 0, stream>>>(ca);

    // ---------------- layer 1 ----------------
    al128f_kernel<<<2048, 256, 0, stream>>>(x, vbuf[0], vbuf[1], xb0, als, ald, N0, S1);
    mdnw_kernel<<<(S1 + 3) / 4, 256, 0, stream>>>(als, ald, offsets3[0], slist3[0], S1, aself, walpha);
    agg128_kernel<<<(S1 + 3) / 4, 256, 0, stream>>>(xb0, walpha, aself, offsets3[0], slist3[0], S1, aggb);
    gemm2_kernel<128, 128><<<dim3(1024 / 128, S1 / 128), 256, 0, stream>>>(
        xb0, 128, wskipb[0], 128,
        aggb, 512, wsrcb[0], 128, 128, 256,
        hb, 1024, bnsum[0], bnsq[0]);
    // BN+ELU -> x1b, fused with L2 al_src
    norm_al_kernel<<<512, 256, 0, stream>>>(hb, bnsum[0], bnsq[0], P(1, 7), P(1, 8),
                                            vbuf[2], x1b, als, S1, 1.f / S1);
    al1024s_kernel<<<64, 256, 0, stream>>>(x1b, vbuf[3], ald, S2);

    // ---------------- layer 2 ----------------
    mdnw_kernel<<<(S2 + 3) / 4, 256, 0, stream>>>(als, ald, offsets3[1], slist3[1], S2, aself, walpha);
    agg1024_kernel<<<S2, 256, 0, stream>>>(x1b, walpha, aself, offsets3[1], slist3[1], aggb);
    gemm2_kernel<128, 64><<<dim3(1024 / 64, S2 / 128), 256, 0, stream>>>(
        x1b, 1024, wskipb[1], 1024,
        aggb, 4096, wsrcb[1], 1024, 1024, 256,
        hb, 1024, bnsum[1], bnsq[1]);
    // BN+ELU -> x2b, fused with L3 al_src
    norm_al_kernel<<<64, 256, 0, stream>>>(hb, bnsum[1], bnsq[1], P(2, 7), P(2, 8),
                                           vbuf[4], x2b, als, S2, 1.f / S2);
    al1024s_kernel<<<8, 256, 0, stream>>>(x2b, vbuf[5], ald, S3);

    // ---------------- layer 3 ----------------
    mdnw_kernel<<<(S3 + 3) / 4, 256, 0, stream>>>(als, ald, offsets3[2], slist3[2], S3, aself, walpha);
    agg1024_kernel<<<S3, 256, 0, stream>>>(x2b, walpha, aself, offsets3[2], slist3[2], aggb);
    gemm3_splitk<<<dim3(256 / 64, S3 / 64, 10), 256, 0, stream>>>(
        x2b, wskipb[2], aggb, wsrcb[2], Cpart);
    bnstat3_kernel<<<8, 256, 0, stream>>>(Cpart, hb32, bnsum[2], bnsq[2]);
    norm_elu_ff<<<(int)(((long)S3 * 256 / 4 + 255) / 256), 256, 0, stream>>>(
        hb32, bnsum[2], bnsq[2], P(3, 7), P(3, 8), (float*)d_out, 256, 1.f / S3, (long)S3 * 256);
}

// Round 12
// 515.914 us; speedup vs baseline: 1.1112x; 1.1112x over previous
//
#include <hip/hip_runtime.h>
#include <math.h>

// ---------------- problem constants (from reference) ----------------
constexpr int N0 = 262144, S1 = 32768, S2 = 4096, S3 = 512;
constexpr int E1 = 327680, E2 = 40960, E3 = 5120;
constexpr float NEG = 0.2f, BN_EPS = 1e-5f;

typedef __attribute__((ext_vector_type(8))) short short8;   // 8 bf16 (4 VGPRs)
typedef __attribute__((ext_vector_type(4))) float f32x4;    // MFMA acc

__device__ __forceinline__ float lrelu(float x) { return x > 0.f ? x : NEG * x; }

__device__ __forceinline__ unsigned short f2b(float f) {  // f32 -> bf16 RNE
    unsigned int u = __float_as_uint(f);
    return (unsigned short)((u + 0x7FFFu + ((u >> 16) & 1u)) >> 16);
}
__device__ __forceinline__ float b2f(unsigned short u) {
    return __uint_as_float(((unsigned int)u) << 16);
}
__device__ __forceinline__ void ld4(const float* __restrict__ p, float* o) {
    float4 v = *(const float4*)p;
    o[0] = v.x; o[1] = v.y; o[2] = v.z; o[3] = v.w;
}

// async global->LDS, 16B per lane; LDS dest = wave-uniform base + lane*16
__device__ __forceinline__ void gload_lds16(const unsigned short* g, unsigned short* l) {
    __builtin_amdgcn_global_load_lds(
        (const __attribute__((address_space(1))) unsigned int*)g,
        (__attribute__((address_space(3))) unsigned int*)l, 16, 0, 0);
}

// ==================== one-shot prep ====================
struct PrepArgs {
    const float* att[6]; const float* wf[6]; float* v[6];
    const float* csrc[6]; unsigned short* cdst[6];
    int* zptr; int zn4;
};

__global__ void prep_kernel(PrepArgs a)
{
    int b = blockIdx.x, t = threadIdx.x;
    if (b < 68) {
        int f, cb;
        if (b < 2)       { f = 0; cb = b; }
        else if (b < 4)  { f = 1; cb = b - 2; }
        else if (b < 20) { f = 2; cb = b - 4; }
        else if (b < 36) { f = 3; cb = b - 20; }
        else if (b < 52) { f = 4; cb = b - 36; }
        else             { f = 5; cb = b - 52; }
        int din = (f < 2) ? 128 : 1024;
        int idx = cb * 256 + t;
        int h = idx / din, k = idx - h * din;
        const float* ar = a.att[f] + h * 256;
        const float* wr = a.wf[f] + (size_t)(h * 256) * din + k;
        float acc = 0.f;
        for (int j = 0; j < 256; ++j) acc += ar[j] * wr[(size_t)j * din];
        a.v[f][idx] = acc;
    } else if (b < 124) {
        int c = b - 68, j, ob;
        if (c < 2)       { j = 0; ob = c; }
        else if (c < 4)  { j = 1; ob = c - 2; }
        else if (c < 20) { j = 2; ob = c - 4; }
        else if (c < 36) { j = 3; ob = c - 20; }
        else if (c < 40) { j = 4; ob = c - 36; }
        else             { j = 5; ob = c - 40; }
        long base = (long)ob * 65536;
        if (j < 5) {
            const float* src = a.csrc[j];
            unsigned short* dst = a.cdst[j];
            for (int it = 0; it < 64; ++it) {
                long e = base + (long)(it * 256 + t) * 4;
                float4 v = *(const float4*)(src + e);
                ushort4 u;
                u.x = f2b(v.x); u.y = f2b(v.y); u.z = f2b(v.z); u.w = f2b(v.w);
                *(ushort4*)(dst + e) = u;
            }
        } else {  // w3 repack: wp[row*4096 + h*1024 + k] = 0.25*w[(h*256+row)*1024+k]
            const float* src = a.csrc[5];
            unsigned short* dst = a.cdst[5];
            for (int it = 0; it < 64; ++it) {
                long e = base + (long)(it * 256 + t) * 4;
                int row = (int)(e >> 12);
                int hk = (int)(e & 4095);
                int h = hk >> 10, k = hk & 1023;
                float4 v = *(const float4*)(src + ((size_t)(h * 256 + row) << 10) + k);
                ushort4 u;
                u.x = f2b(0.25f * v.x); u.y = f2b(0.25f * v.y);
                u.z = f2b(0.25f * v.z); u.w = f2b(0.25f * v.w);
                *(ushort4*)(dst + e) = u;
            }
        }
    } else {
        int i = (b - 124) * 256 + t;
        if (i < a.zn4) ((int4*)a.zptr)[i] = make_int4(0, 0, 0, 0);
    }
}

// ==================== CSR build for ALL layers (input-only) ====================
struct CsrArgs {
    const int* edst[3]; const int* esrc[3];
    int* counts[3]; int* offsets[3]; int* cursor[3]; int* slist[3];
    int sizes[3];
};

__global__ void count_all(CsrArgs a)
{
    int id = blockIdx.x * 256 + threadIdx.x;
    int L, e;
    if (id < E1)           { L = 0; e = id; }
    else if (id < E1 + E2) { L = 1; e = id - E1; }
    else if (id < E1 + E2 + E3) { L = 2; e = id - E1 - E2; }
    else return;
    atomicAdd(&a.counts[L][a.edst[L][e]], 1);
}

__global__ void scan_all(CsrArgs a)
{
    __shared__ int lds[1024];
    int L = blockIdx.x;
    int size = a.sizes[L];
    const int* counts = a.counts[L];
    int* offsets = a.offsets[L];
    int* cursor = a.cursor[L];
    int t = threadIdx.x;
    int chunk = (size + 1023) >> 10;
    int begin = t * chunk;
    int end = begin + chunk; if (end > size) end = size;
    if (begin > size) begin = size;
    int s = 0;
    if ((chunk & 3) == 0) {
        for (int i = begin; i < end; i += 4) {
            int4 v = *(const int4*)(counts + i);
            s += v.x + v.y + v.z + v.w;
        }
    } else {
        for (int i = begin; i < end; ++i) s += counts[i];
    }
    lds[t] = s;
    __syncthreads();
    for (int d = 1; d < 1024; d <<= 1) {
        int v = (t >= d) ? lds[t - d] : 0;
        __syncthreads();
        lds[t] += v;
        __syncthreads();
    }
    int base = (t > 0) ? lds[t - 1] : 0;
    for (int i = begin; i < end; ++i) {
        offsets[i] = base; cursor[i] = base;
        base += counts[i];
    }
    if (t == 1023) offsets[size] = lds[1023];
}

__global__ void scatter_all(CsrArgs a)
{
    int id = blockIdx.x * 256 + threadIdx.x;
    int L, e;
    if (id < E1)           { L = 0; e = id; }
    else if (id < E1 + E2) { L = 1; e = id - E1; }
    else if (id < E1 + E2 + E3) { L = 2; e = id - E1 - E2; }
    else return;
    int p = atomicAdd(&a.cursor[L][a.edst[L][e]], 1);
    a.slist[L][p] = a.esrc[L][e];
}

// ==================== L1: fused f32->bf16 conv + al_src + al_dst ====================
// unroll-2: each 32-lane half processes 2 consecutive nodes per iteration (2 loads in flight)
__global__ void al128f_kernel(const float* __restrict__ x, const float* __restrict__ vs,
                              const float* __restrict__ vd, unsigned short* __restrict__ xb,
                              float* __restrict__ als, float* __restrict__ ald, int n, int ndst)
{
    int lane = threadIdx.x & 63;
    int wave = (blockIdx.x * 256 + threadIdx.x) >> 6;
    int nw = (gridDim.x * 256) >> 6;
    int j32 = lane & 31, half = lane >> 5;
    float vsr[4][4], vdr[4][4];
    #pragma unroll
    for (int h = 0; h < 4; ++h) {
        ld4(vs + h * 128 + j32 * 4, vsr[h]);
        ld4(vd + h * 128 + j32 * 4, vdr[h]);
    }
    // n % 4 == 0 and ndst % 4 == 0: pair (base, base+1) never straddles n or ndst
    for (long base = (long)wave * 4 + half * 2; base < n; base += (long)nw * 4) {
        float4 xv0 = *(const float4*)(x + base * 128 + j32 * 4);
        float4 xv1 = *(const float4*)(x + (base + 1) * 128 + j32 * 4);
        ushort4 u0, u1;
        u0.x = f2b(xv0.x); u0.y = f2b(xv0.y); u0.z = f2b(xv0.z); u0.w = f2b(xv0.w);
        u1.x = f2b(xv1.x); u1.y = f2b(xv1.y); u1.z = f2b(xv1.z); u1.w = f2b(xv1.w);
        *(ushort4*)(xb + base * 128 + j32 * 4) = u0;
        *(ushort4*)(xb + (base + 1) * 128 + j32 * 4) = u1;
        float f0[4] = { xv0.x, xv0.y, xv0.z, xv0.w };
        float f1[4] = { xv1.x, xv1.y, xv1.z, xv1.w };
        float a0[4], a1[4], b0[4], b1[4];
        bool isd = base < ndst;   // uniform for the pair and within the half
        #pragma unroll
        for (int h = 0; h < 4; ++h) {
            a0[h] = f0[0]*vsr[h][0] + f0[1]*vsr[h][1] + f0[2]*vsr[h][2] + f0[3]*vsr[h][3];
            a1[h] = f1[0]*vsr[h][0] + f1[1]*vsr[h][1] + f1[2]*vsr[h][2] + f1[3]*vsr[h][3];
        }
        if (isd) {
            #pragma unroll
            for (int h = 0; h < 4; ++h) {
                b0[h] = f0[0]*vdr[h][0] + f0[1]*vdr[h][1] + f0[2]*vdr[h][2] + f0[3]*vdr[h][3];
                b1[h] = f1[0]*vdr[h][0] + f1[1]*vdr[h][1] + f1[2]*vdr[h][2] + f1[3]*vdr[h][3];
            }
        }
        #pragma unroll
        for (int off = 16; off > 0; off >>= 1) {
            #pragma unroll
            for (int h = 0; h < 4; ++h) {
                a0[h] += __shfl_xor(a0[h], off);
                a1[h] += __shfl_xor(a1[h], off);
            }
            if (isd)
                #pragma unroll
                for (int h = 0; h < 4; ++h) {
                    b0[h] += __shfl_xor(b0[h], off);
                    b1[h] += __shfl_xor(b1[h], off);
                }
        }
        if (j32 == 0) {
            *(float4*)(als + base * 4) = make_float4(a0[0], a0[1], a0[2], a0[3]);
            *(float4*)(als + (base + 1) * 4) = make_float4(a1[0], a1[1], a1[2], a1[3]);
            if (isd) {
                *(float4*)(ald + base * 4) = make_float4(b0[0], b0[1], b0[2], b0[3]);
                *(float4*)(ald + (base + 1) * 4) = make_float4(b1[0], b1[1], b1[2], b1[3]);
            }
        }
    }
}

// ==================== L2/L3: al src+dst in ONE launch (grid split) ====================
__global__ void al1024d_kernel(const unsigned short* __restrict__ xb,
                               const float* __restrict__ vs, const float* __restrict__ vd,
                               float* __restrict__ als, float* __restrict__ ald,
                               int nsrc, int ndst, int bsrc)
{
    bool isdst = (int)blockIdx.x >= bsrc;
    const float* v = isdst ? vd : vs;
    float* al = isdst ? ald : als;
    int n = isdst ? ndst : nsrc;
    int b0 = isdst ? blockIdx.x - bsrc : blockIdx.x;
    int nb = isdst ? gridDim.x - bsrc : bsrc;
    int lane = threadIdx.x & 63;
    int wave = (b0 * 256 + threadIdx.x) >> 6;
    int nwaves = (nb * 256) >> 6;
    float vr[4][16];
    #pragma unroll
    for (int h = 0; h < 4; ++h)
        #pragma unroll
        for (int it = 0; it < 2; ++it) {
            ld4(v + h * 1024 + it * 512 + lane * 8,     &vr[h][it * 8]);
            ld4(v + h * 1024 + it * 512 + lane * 8 + 4, &vr[h][it * 8 + 4]);
        }
    for (long node = wave; node < n; node += nwaves) {
        const unsigned short* xr = xb + node * 1024;
        float a[4] = {0.f, 0.f, 0.f, 0.f};
        #pragma unroll
        for (int it = 0; it < 2; ++it) {
            short8 u = *(const short8*)(xr + it * 512 + lane * 8);
            #pragma unroll
            for (int j = 0; j < 8; ++j) {
                float xv = b2f((unsigned short)u[j]);
                #pragma unroll
                for (int h = 0; h < 4; ++h) a[h] += xv * vr[h][it * 8 + j];
            }
        }
        #pragma unroll
        for (int off = 32; off > 0; off >>= 1)
            #pragma unroll
            for (int h = 0; h < 4; ++h) a[h] += __shfl_xor(a[h], off);
        if (lane == 0) *(float4*)(al + node * 4) = make_float4(a[0], a[1], a[2], a[3]);
    }
}

// ==================== wave-parallel softmax stats + per-slot alpha ====================
__global__ void mdnw_kernel(const float* __restrict__ als, const float* __restrict__ ald,
                            const int* __restrict__ offsets, const int* __restrict__ slist,
                            int size, float* __restrict__ aself, float* __restrict__ walpha)
{
    int d = blockIdx.x * 4 + (threadIdx.x >> 6);
    if (d >= size) return;
    int lane = threadIdx.x & 63;
    float ad[4], sl[4], q[4];
    ld4(ald + 4 * (size_t)d, ad);
    ld4(als + 4 * (size_t)d, q);
    #pragma unroll
    for (int h = 0; h < 4; ++h) sl[h] = lrelu(q[h] + ad[h]);
    int beg = offsets[d], deg = offsets[d + 1] - beg;
    float m[4] = { sl[0], sl[1], sl[2], sl[3] };
    for (int p = lane; p < deg; p += 64) {
        int s = slist[beg + p];
        ld4(als + 4 * (size_t)s, q);
        #pragma unroll
        for (int h = 0; h < 4; ++h) m[h] = fmaxf(m[h], lrelu(q[h] + ad[h]));
    }
    #pragma unroll
    for (int off = 32; off > 0; off >>= 1)
        #pragma unroll
        for (int h = 0; h < 4; ++h) m[h] = fmaxf(m[h], __shfl_xor(m[h], off));
    float dn[4] = {0.f, 0.f, 0.f, 0.f};
    for (int p = lane; p < deg; p += 64) {
        int s = slist[beg + p];
        ld4(als + 4 * (size_t)s, q);
        #pragma unroll
        for (int h = 0; h < 4; ++h) dn[h] += expf(lrelu(q[h] + ad[h]) - m[h]);
    }
    #pragma unroll
    for (int off = 32; off > 0; off >>= 1)
        #pragma unroll
        for (int h = 0; h < 4; ++h) dn[h] += __shfl_xor(dn[h], off);
    float r[4];
    #pragma unroll
    for (int h = 0; h < 4; ++h)
        r[h] = 1.f / (dn[h] + expf(sl[h] - m[h]) + 1e-16f);
    if (lane == 0) {
        float4 w;
        w.x = expf(sl[0] - m[0]) * r[0];
        w.y = expf(sl[1] - m[1]) * r[1];
        w.z = expf(sl[2] - m[2]) * r[2];
        w.w = expf(sl[3] - m[3]) * r[3];
        *(float4*)(aself + 4 * (size_t)d) = w;
    }
    for (int p = lane; p < deg; p += 64) {
        int s = slist[beg + p];
        ld4(als + 4 * (size_t)s, q);
        float4 w;
        w.x = expf(lrelu(q[0] + ad[0]) - m[0]) * r[0];
        w.y = expf(lrelu(q[1] + ad[1]) - m[1]) * r[1];
        w.z = expf(lrelu(q[2] + ad[2]) - m[2]) * r[2];
        w.w = expf(lrelu(q[3] + ad[3]) - m[3]) * r[3];
        *(float4*)(walpha + 4 * (size_t)(beg + p)) = w;
    }
}

// ==================== aggregation (slot-indexed alpha, direct src ids) ====================
// 4 dsts per 256-thread block (one wave each)
__global__ void agg128_kernel(const unsigned short* __restrict__ xb, const float* __restrict__ walpha,
                              const float* __restrict__ aself,
                              const int* __restrict__ offsets, const int* __restrict__ slist,
                              int size, unsigned short* __restrict__ aggb)
{
    int d = blockIdx.x * 4 + (threadIdx.x >> 6);
    if (d >= size) return;
    int lane = threadIdx.x & 63;
    int beg = offsets[d], end = offsets[d + 1];
    float w[4], acc[4][2];
    ld4(aself + 4 * (size_t)d, w);
    {
        unsigned int u = *(const unsigned int*)(xb + (size_t)d * 128 + lane * 2);
        float x0 = b2f((unsigned short)(u & 0xFFFF)), x1 = b2f((unsigned short)(u >> 16));
        #pragma unroll
        for (int h = 0; h < 4; ++h) { acc[h][0] = w[h] * x0; acc[h][1] = w[h] * x1; }
    }
    for (int p = beg; p < end; ++p) {
        int s = slist[p];
        ld4(walpha + 4 * (size_t)p, w);
        unsigned int u = *(const unsigned int*)(xb + (size_t)s * 128 + lane * 2);
        float x0 = b2f((unsigned short)(u & 0xFFFF)), x1 = b2f((unsigned short)(u >> 16));
        #pragma unroll
        for (int h = 0; h < 4; ++h) { acc[h][0] += w[h] * x0; acc[h][1] += w[h] * x1; }
    }
    unsigned int* og = (unsigned int*)(aggb + (size_t)d * 512);
    #pragma unroll
    for (int h = 0; h < 4; ++h)
        og[h * 64 + lane] = (unsigned int)f2b(acc[h][0]) | ((unsigned int)f2b(acc[h][1]) << 16);
}

__global__ void agg1024_kernel(const unsigned short* __restrict__ xb, const float* __restrict__ walpha,
                               const float* __restrict__ aself,
                               const int* __restrict__ offsets, const int* __restrict__ slist,
                               unsigned short* __restrict__ aggb)
{
    int d = blockIdx.x, t = threadIdx.x;
    int beg = offsets[d], end = offsets[d + 1];
    float w[4], acc[4][4];
    ld4(aself + 4 * (size_t)d, w);
    {
        ushort4 u = *(const ushort4*)(xb + (size_t)d * 1024 + t * 4);
        float xv[4] = { b2f(u.x), b2f(u.y), b2f(u.z), b2f(u.w) };
        #pragma unroll
        for (int h = 0; h < 4; ++h)
            #pragma unroll
            for (int j = 0; j < 4; ++j) acc[h][j] = w[h] * xv[j];
    }
    for (int p = beg; p < end; ++p) {
        int s = slist[p];
        ld4(walpha + 4 * (size_t)p, w);
        ushort4 u = *(const ushort4*)(xb + (size_t)s * 1024 + t * 4);
        float xv[4] = { b2f(u.x), b2f(u.y), b2f(u.z), b2f(u.w) };
        #pragma unroll
        for (int h = 0; h < 4; ++h)
            #pragma unroll
            for (int j = 0; j < 4; ++j) acc[h][j] += w[h] * xv[j];
    }
    unsigned short* og = aggb + (size_t)d * 4096;
    #pragma unroll
    for (int h = 0; h < 4; ++h) {
        ushort4 u;
        u.x = f2b(acc[h][0]); u.y = f2b(acc[h][1]);
        u.z = f2b(acc[h][2]); u.w = f2b(acc[h][3]);
        *(ushort4*)(og + h * 1024 + t * 4) = u;
    }
}

// ==================== fused dual-phase bf16 MFMA GEMM + BN stats (L1/L2) ====================
#define SWZ(r, c) ((((c) ^ (((r) >> 1) & 3)) << 3))

template<int BM, int BN>
__global__ __launch_bounds__(256) void gemm2_kernel(
    const unsigned short* __restrict__ A1, int lda1, const unsigned short* __restrict__ W1, int K1,
    const unsigned short* __restrict__ A2, int lda2, const unsigned short* __restrict__ W2, int K2,
    int hs2, int cph2,
    unsigned short* __restrict__ C, int N,
    float* __restrict__ bnsum, float* __restrict__ bnsq)
{
    constexpr int WM = BM / 2, WN = BN / 2;
    constexpr int TM = WM / 16, TN = WN / 16;
    constexpr int APASS = (BM * 4) / 256, BPASS = (BN * 4) / 256;
    __shared__ __align__(16) unsigned short As[BM * 32];
    __shared__ __align__(16) unsigned short Bs[BN * 32];
    __shared__ float sbn[2 * BN];
    int tid = threadIdx.x;
    int gx = gridDim.x;
    int nwg = gx * gridDim.y;
    int bid = blockIdx.y * gx + blockIdx.x;
    int cpx = nwg >> 3;
    int swz = (bid & 7) * cpx + (bid >> 3);
    int n0 = (swz % gx) * BN, m0 = (swz / gx) * BM;
    int l = tid & 63, l16 = l & 15, kq = l >> 4;
    int wid = tid >> 6, wr = wid >> 1, wc = wid & 1;

    f32x4 acc[TM][TN];
    #pragma unroll
    for (int mi = 0; mi < TM; ++mi)
        #pragma unroll
        for (int ni = 0; ni < TN; ++ni) acc[mi][ni] = (f32x4){0.f, 0.f, 0.f, 0.f};

    #pragma unroll
    for (int ph = 0; ph < 2; ++ph) {
        const unsigned short* Ap = ph ? A2 + (size_t)m0 * lda2 + (cph2 ? (size_t)(n0 / cph2) * hs2 : 0)
                                      : A1 + (size_t)m0 * lda1;
        int lda = ph ? lda2 : lda1;
        const unsigned short* Wp = ph ? W2 + (size_t)n0 * K2 : W1 + (size_t)n0 * K1;
        int ldw = ph ? K2 : K1;
        int K = ph ? K2 : K1;
        for (int k0 = 0; k0 < K; k0 += 32) {
            #pragma unroll
            for (int ps = 0; ps < APASS; ++ps) {
                int sbase = ps * 256 + wid * 64;
                int s = sbase + l;
                int r = s >> 2, cc = s & 3;
                gload_lds16(Ap + (size_t)r * lda + k0 + ((cc ^ ((r >> 1) & 3)) << 3),
                            &As[(size_t)sbase * 8]);
            }
            #pragma unroll
            for (int ps = 0; ps < BPASS; ++ps) {
                int sbase = ps * 256 + wid * 64;
                int s = sbase + l;
                int r = s >> 2, cc = s & 3;
                gload_lds16(Wp + (size_t)r * ldw + k0 + ((cc ^ ((r >> 1) & 3)) << 3),
                            &Bs[(size_t)sbase * 8]);
            }
            __syncthreads();
            short8 af[TM], bfr[TN];
            #pragma unroll
            for (int mi = 0; mi < TM; ++mi) {
                int r = wr * WM + mi * 16 + l16;
                af[mi] = *(const short8*)&As[r * 32 + SWZ(r, kq)];
            }
            #pragma unroll
            for (int ni = 0; ni < TN; ++ni) {
                int r = wc * WN + ni * 16 + l16;
                bfr[ni] = *(const short8*)&Bs[r * 32 + SWZ(r, kq)];
            }
            #pragma unroll
            for (int mi = 0; mi < TM; ++mi)
                #pragma unroll
                for (int ni = 0; ni < TN; ++ni)
                    acc[mi][ni] = __builtin_amdgcn_mfma_f32_16x16x32_bf16(
                        af[mi], bfr[ni], acc[mi][ni], 0, 0, 0);
            __syncthreads();
        }
    }

    if (tid < 2 * BN) sbn[tid] = 0.f;
    __syncthreads();

    #pragma unroll
    for (int ni = 0; ni < TN; ++ni) {
        int col = wc * WN + ni * 16 + l16;
        float s = 0.f, q = 0.f;
        #pragma unroll
        for (int mi = 0; mi < TM; ++mi) {
            int rowb = wr * WM + mi * 16 + (kq << 2);
            #pragma unroll
            for (int r = 0; r < 4; ++r) {
                float v = acc[mi][ni][r];
                C[(size_t)(m0 + rowb + r) * N + n0 + col] = f2b(v);
                s += v; q += v * v;
            }
        }
        atomicAdd(&sbn[col * 2 + 0], s);
        atomicAdd(&sbn[col * 2 + 1], q);
    }
    __syncthreads();
    if (tid < BN) {
        atomicAdd(&bnsum[n0 + tid], sbn[tid * 2 + 0]);
        atomicAdd(&bnsq[n0 + tid], sbn[tid * 2 + 1]);
    }
}

// ==================== L3: split-K GEMM -> Cpart[z][512][256] (deterministic) ====================
__global__ __launch_bounds__(256) void gemm3_splitk(
    const unsigned short* __restrict__ A1, const unsigned short* __restrict__ W1,
    const unsigned short* __restrict__ A2, const unsigned short* __restrict__ W2,
    float* __restrict__ Cpart)
{
    constexpr int BM = 64, BN = 64, WM = 32, WN = 32, TM = 2, TN = 2;
    __shared__ __align__(16) unsigned short As[BM * 32];
    __shared__ __align__(16) unsigned short Bs[BN * 32];
    int tid = threadIdx.x;
    int n0 = blockIdx.x * BN, m0 = blockIdx.y * BM;
    int z = blockIdx.z;
    int ph = (z >= 2);
    int ks = ph ? (z - 2) * 512 : z * 512;
    const unsigned short* Ap = ph ? A2 + (size_t)m0 * 4096 : A1 + (size_t)m0 * 1024;
    const unsigned short* Wp = ph ? W2 + (size_t)n0 * 4096 : W1 + (size_t)n0 * 1024;
    int lda = ph ? 4096 : 1024;
    int l = tid & 63, l16 = l & 15, kq = l >> 4;
    int wid = tid >> 6, wr = wid >> 1, wc = wid & 1;

    f32x4 acc[TM][TN];
    #pragma unroll
    for (int mi = 0; mi < TM; ++mi)
        #pragma unroll
        for (int ni = 0; ni < TN; ++ni) acc[mi][ni] = (f32x4){0.f, 0.f, 0.f, 0.f};

    for (int k0 = ks; k0 < ks + 512; k0 += 32) {
        {
            int sbase = wid * 64;
            int s = sbase + l;
            int r = s >> 2, cc = s & 3;
            gload_lds16(Ap + (size_t)r * lda + k0 + ((cc ^ ((r >> 1) & 3)) << 3),
                        &As[(size_t)sbase * 8]);
            gload_lds16(Wp + (size_t)r * lda + k0 + ((cc ^ ((r >> 1) & 3)) << 3),
                        &Bs[(size_t)sbase * 8]);
        }
        __syncthreads();
        short8 af[TM], bfr[TN];
        #pragma unroll
        for (int mi = 0; mi < TM; ++mi) {
            int r = wr * WM + mi * 16 + l16;
            af[mi] = *(const short8*)&As[r * 32 + SWZ(r, kq)];
        }
        #pragma unroll
        for (int ni = 0; ni < TN; ++ni) {
            int r = wc * WN + ni * 16 + l16;
            bfr[ni] = *(const short8*)&Bs[r * 32 + SWZ(r, kq)];
        }
        #pragma unroll
        for (int mi = 0; mi < TM; ++mi)
            #pragma unroll
            for (int ni = 0; ni < TN; ++ni)
                acc[mi][ni] = __builtin_amdgcn_mfma_f32_16x16x32_bf16(
                    af[mi], bfr[ni], acc[mi][ni], 0, 0, 0);
        __syncthreads();
    }

    float* Cz = Cpart + (size_t)z * S3 * 256;
    #pragma unroll
    for (int ni = 0; ni < TN; ++ni) {
        int col = wc * WN + ni * 16 + l16;
        #pragma unroll
        for (int mi = 0; mi < TM; ++mi) {
            int rowb = wr * WM + mi * 16 + (kq << 2);
            #pragma unroll
            for (int r = 0; r < 4; ++r)
                Cz[(size_t)(m0 + rowb + r) * 256 + n0 + col] = acc[mi][ni][r];
        }
    }
}

// reduce Cpart over z -> hb32, accumulate BN column stats
__global__ void bnstat3_kernel(const float* __restrict__ Cpart, float* __restrict__ hb32,
                               float* __restrict__ bnsum, float* __restrict__ bnsq)
{
    int c = threadIdx.x;
    int r0 = blockIdx.x * 64;
    float s = 0.f, q = 0.f;
    for (int r = r0; r < r0 + 64; ++r) {
        float v = 0.f;
        #pragma unroll
        for (int z = 0; z < 10; ++z)
            v += Cpart[((size_t)z * S3 + r) * 256 + c];
        hb32[(size_t)r * 256 + c] = v;
        s += v; q += v * v;
    }
    atomicAdd(&bnsum[c], s);
    atomicAdd(&bnsq[c], q);
}

// ==================== BN finalize fused into apply + ELU (8 elems/thread) ====================
__global__ void norm_elu_bb(const unsigned short* __restrict__ h,
                            const float* __restrict__ sum, const float* __restrict__ sq,
                            const float* __restrict__ gamma, const float* __restrict__ beta,
                            unsigned short* __restrict__ out, int N, float invM, long total)
{
    long i0 = ((long)blockIdx.x * 256 + threadIdx.x) * 8;
    if (i0 >= total) return;
    #pragma unroll
    for (int g = 0; g < 2; ++g) {
        long i = i0 + g * 4;
        int c = (int)(i % N);
        float4 sm = *(const float4*)(sum + c);
        float4 qq = *(const float4*)(sq + c);
        float4 gm = *(const float4*)(gamma + c);
        float4 bt = *(const float4*)(beta + c);
        float mu0 = sm.x * invM, mu1 = sm.y * invM, mu2 = sm.z * invM, mu3 = sm.w * invM;
        float sc0 = gm.x * rsqrtf(qq.x * invM - mu0 * mu0 + BN_EPS);
        float sc1 = gm.y * rsqrtf(qq.y * invM - mu1 * mu1 + BN_EPS);
        float sc2 = gm.z * rsqrtf(qq.z * invM - mu2 * mu2 + BN_EPS);
        float sc3 = gm.w * rsqrtf(qq.w * invM - mu3 * mu3 + BN_EPS);
        float sh0 = bt.x - mu0 * sc0, sh1 = bt.y - mu1 * sc1;
        float sh2 = bt.z - mu2 * sc2, sh3 = bt.w - mu3 * sc3;
        ushort4 u = *(const ushort4*)(h + i);
        float v0 = b2f(u.x) * sc0 + sh0;
        float v1 = b2f(u.y) * sc1 + sh1;
        float v2 = b2f(u.z) * sc2 + sh2;
        float v3 = b2f(u.w) * sc3 + sh3;
        v0 = v0 > 0.f ? v0 : expm1f(v0);
        v1 = v1 > 0.f ? v1 : expm1f(v1);
        v2 = v2 > 0.f ? v2 : expm1f(v2);
        v3 = v3 > 0.f ? v3 : expm1f(v3);
        ushort4 o;
        o.x = f2b(v0); o.y = f2b(v1); o.z = f2b(v2); o.w = f2b(v3);
        *(ushort4*)(out + i) = o;
    }
}

__global__ void norm_elu_ff(const float* __restrict__ h,
                            const float* __restrict__ sum, const float* __restrict__ sq,
                            const float* __restrict__ gamma, const float* __restrict__ beta,
                            float* __restrict__ out, int N, float invM, long total)
{
    long i = ((long)blockIdx.x * 256 + threadIdx.x) * 4;
    if (i >= total) return;
    int c = (int)(i % N);
    float4 sm = *(const float4*)(sum + c);
    float4 qq = *(const float4*)(sq + c);
    float4 gm = *(const float4*)(gamma + c);
    float4 bt = *(const float4*)(beta + c);
    float mu0 = sm.x * invM, mu1 = sm.y * invM, mu2 = sm.z * invM, mu3 = sm.w * invM;
    float sc0 = gm.x * rsqrtf(qq.x * invM - mu0 * mu0 + BN_EPS);
    float sc1 = gm.y * rsqrtf(qq.y * invM - mu1 * mu1 + BN_EPS);
    float sc2 = gm.z * rsqrtf(qq.z * invM - mu2 * mu2 + BN_EPS);
    float sc3 = gm.w * rsqrtf(qq.w * invM - mu3 * mu3 + BN_EPS);
    float4 hv = *(const float4*)(h + i);
    float4 o;
    o.x = hv.x * sc0 + (bt.x - mu0 * sc0);
    o.y = hv.y * sc1 + (bt.y - mu1 * sc1);
    o.z = hv.z * sc2 + (bt.z - mu2 * sc2);
    o.w = hv.w * sc3 + (bt.w - mu3 * sc3);
    o.x = o.x > 0.f ? o.x : expm1f(o.x);
    o.y = o.y > 0.f ? o.y : expm1f(o.y);
    o.z = o.z > 0.f ? o.z : expm1f(o.z);
    o.w = o.w > 0.f ? o.w : expm1f(o.w);
    *(float4*)(out + i) = o;
}

// =====================================================================
extern "C" void kernel_launch(void* const* d_in, const int* in_sizes, int n_in,
                              void* d_out, int out_size, void* d_ws, size_t ws_size,
                              hipStream_t stream)
{
    const float* x = (const float*)d_in[0];
    auto P = [&](int layer, int slot) -> const float* {
        return (const float*)d_in[1 + (layer - 1) * 9 + slot];
    };
    const int* edge_src[3] = { (const int*)d_in[28], (const int*)d_in[30], (const int*)d_in[32] };
    const int* edge_dst[3] = { (const int*)d_in[29], (const int*)d_in[31], (const int*)d_in[33] };

    // -------- workspace carve --------
    char* wsb = (char*)d_ws;
    size_t off = 0;
    auto alloc = [&](size_t bytes) -> void* {
        void* p = wsb + off;
        off = (off + bytes + 255) & ~(size_t)255;
        return p;
    };
    unsigned short* xb0   = (unsigned short*)alloc((size_t)N0 * 128 * 2);
    unsigned short* x1b   = (unsigned short*)alloc((size_t)S1 * 1024 * 2);
    unsigned short* x2b   = (unsigned short*)alloc((size_t)S2 * 1024 * 2);
    unsigned short* hb    = (unsigned short*)alloc((size_t)S1 * 1024 * 2);
    unsigned short* aggb  = (unsigned short*)alloc((size_t)S2 * 4096 * 2);
    unsigned short* wskipb[3] = {
        (unsigned short*)alloc(131072 * 2),
        (unsigned short*)alloc(1048576 * 2),
        (unsigned short*)alloc(262144 * 2) };
    unsigned short* wsrcb[3] = {
        (unsigned short*)alloc(131072 * 2),
        (unsigned short*)alloc(1048576 * 2),
        (unsigned short*)alloc(1048576 * 2) };
    float* vbuf[6];
    vbuf[0] = (float*)alloc(512 * 4);
    vbuf[1] = (float*)alloc(512 * 4);
    vbuf[2] = (float*)alloc(4096 * 4);
    vbuf[3] = (float*)alloc(4096 * 4);
    vbuf[4] = (float*)alloc(4096 * 4);
    vbuf[5] = (float*)alloc(4096 * 4);
    float* als     = (float*)alloc((size_t)N0 * 4 * 4);
    float* ald     = (float*)alloc((size_t)S1 * 4 * 4);
    float* aself   = (float*)alloc((size_t)S1 * 4 * 4);
    float* walpha  = (float*)alloc((size_t)E1 * 4 * 4);
    float* Cpart   = (float*)alloc((size_t)10 * S3 * 256 * 4);
    float* hb32    = (float*)alloc((size_t)S3 * 256 * 4);
    int* offsets3[3] = { (int*)alloc((S1 + 1) * 4), (int*)alloc((S2 + 1) * 4), (int*)alloc((S3 + 1) * 4) };
    int* cursor3 [3] = { (int*)alloc(S1 * 4), (int*)alloc(S2 * 4), (int*)alloc(S3 * 4) };
    int* slist3  [3] = { (int*)alloc(E1 * 4), (int*)alloc(E2 * 4), (int*)alloc(E3 * 4) };
    int zn = S1 + S2 + S3 + 6 * 1024;
    int* zreg = (int*)alloc((size_t)zn * 4);
    int* counts[3] = { zreg, zreg + S1, zreg + S1 + S2 };
    float* bnsum[3] = { (float*)(zreg + S1 + S2 + S3),
                        (float*)(zreg + S1 + S2 + S3 + 2048),
                        (float*)(zreg + S1 + S2 + S3 + 4096) };
    float* bnsq[3]  = { bnsum[0] + 1024, bnsum[1] + 1024, bnsum[2] + 1024 };

    // -------- one-shot prep: folds + weight bf16 + zeroing --------
    PrepArgs pa;
    for (int L = 0; L < 3; ++L) {
        pa.att[2 * L]     = P(L + 1, 2); pa.wf[2 * L]     = P(L + 1, 0); pa.v[2 * L]     = vbuf[2 * L];
        pa.att[2 * L + 1] = P(L + 1, 3); pa.wf[2 * L + 1] = P(L + 1, 1); pa.v[2 * L + 1] = vbuf[2 * L + 1];
    }
    pa.csrc[0] = P(1, 5); pa.cdst[0] = wskipb[0];
    pa.csrc[1] = P(1, 0); pa.cdst[1] = wsrcb[0];
    pa.csrc[2] = P(2, 5); pa.cdst[2] = wskipb[1];
    pa.csrc[3] = P(2, 0); pa.cdst[3] = wsrcb[1];
    pa.csrc[4] = P(3, 5); pa.cdst[4] = wskipb[2];
    pa.csrc[5] = P(3, 0); pa.cdst[5] = wsrcb[2];
    pa.zptr = zreg; pa.zn4 = zn / 4;
    prep_kernel<<<167, 256, 0, stream>>>(pa);

    // -------- CSR build for all layers --------
    CsrArgs ca;
    for (int L = 0; L < 3; ++L) {
        ca.edst[L] = edge_dst[L]; ca.esrc[L] = edge_src[L];
        ca.counts[L] = counts[L]; ca.offsets[L] = offsets3[L];
        ca.cursor[L] = cursor3[L]; ca.slist[L] = slist3[L];
    }
    ca.sizes[0] = S1; ca.sizes[1] = S2; ca.sizes[2] = S3;
    count_all<<<(E1 + E2 + E3) / 256, 256, 0, stream>>>(ca);
    scan_all<<<3, 1024, 0, stream>>>(ca);
    scatter_all<<<(E1 + E2 + E3) / 256, 256, 0, stream>>>(ca);

    // ---------------- layer 1 ----------------
    al128f_kernel<<<2048, 256, 0, stream>>>(x, vbuf[0], vbuf[1], xb0, als, ald, N0, S1);
    mdnw_kernel<<<(S1 + 3) / 4, 256, 0, stream>>>(als, ald, offsets3[0], slist3[0], S1, aself, walpha);
    agg128_kernel<<<(S1 + 3) / 4, 256, 0, stream>>>(xb0, walpha, aself, offsets3[0], slist3[0], S1, aggb);
    gemm2_kernel<128, 128><<<dim3(1024 / 128, S1 / 128), 256, 0, stream>>>(
        xb0, 128, wskipb[0], 128,
        aggb, 512, wsrcb[0], 128, 128, 256,
        hb, 1024, bnsum[0], bnsq[0]);
    norm_elu_bb<<<(int)(((long)S1 * 1024 / 8 + 255) / 256), 256, 0, stream>>>(
        hb, bnsum[0], bnsq[0], P(1, 7), P(1, 8), x1b, 1024, 1.f / S1, (long)S1 * 1024);

    // ---------------- layer 2 ----------------
    al1024d_kernel<<<576, 256, 0, stream>>>(x1b, vbuf[2], vbuf[3], als, ald, S1, S2, 512);
    mdnw_kernel<<<(S2 + 3) / 4, 256, 0, stream>>>(als, ald, offsets3[1], slist3[1], S2, aself, walpha);
    agg1024_kernel<<<S2, 256, 0, stream>>>(x1b, walpha, aself, offsets3[1], slist3[1], aggb);
    gemm2_kernel<64, 64><<<dim3(1024 / 64, S2 / 64), 256, 0, stream>>>(
        x1b, 1024, wskipb[1], 1024,
        aggb, 4096, wsrcb[1], 1024, 1024, 256,
        hb, 1024, bnsum[1], bnsq[1]);
    norm_elu_bb<<<(int)(((long)S2 * 1024 / 8 + 255) / 256), 256, 0, stream>>>(
        hb, bnsum[1], bnsq[1], P(2, 7), P(2, 8), x2b, 1024, 1.f / S2, (long)S2 * 1024);

    // ---------------- layer 3 ----------------
    al1024d_kernel<<<72, 256, 0, stream>>>(x2b, vbuf[4], vbuf[5], als, ald, S2, S3, 64);
    mdnw_kernel<<<(S3 + 3) / 4, 256, 0, stream>>>(als, ald, offsets3[2], slist3[2], S3, aself, walpha);
    agg1024_kernel<<<S3, 256, 0, stream>>>(x2b, walpha, aself, offsets3[2], slist3[2], aggb);
    gemm3_splitk<<<dim3(256 / 64, S3 / 64, 10), 256, 0, stream>>>(
        x2b, wskipb[2], aggb, wsrcb[2], Cpart);
    bnstat3_kernel<<<8, 256, 0, stream>>>(Cpart, hb32, bnsum[2], bnsq[2]);
    norm_elu_ff<<<(int)(((long)S3 * 256 / 4 + 255) / 256), 256, 0, stream>>>(
        hb32, bnsum[2], bnsq[2], P(3, 7), P(3, 8), (float*)d_out, 256, 1.f / S3, (long)S3 * 256);
}

// Round 13
// 511.131 us; speedup vs baseline: 1.1216x; 1.0094x over previous
//
#include <hip/hip_runtime.h>
#include <math.h>

// ---------------- problem constants (from reference) ----------------
constexpr int N0 = 262144, S1 = 32768, S2 = 4096, S3 = 512;
constexpr int E1 = 327680, E2 = 40960, E3 = 5120;
constexpr float NEG = 0.2f, BN_EPS = 1e-5f;

typedef __attribute__((ext_vector_type(8))) short short8;   // 8 bf16 (4 VGPRs)
typedef __attribute__((ext_vector_type(4))) float f32x4;    // MFMA acc

__device__ __forceinline__ float lrelu(float x) { return x > 0.f ? x : NEG * x; }

__device__ __forceinline__ unsigned short f2b(float f) {  // f32 -> bf16 RNE
    unsigned int u = __float_as_uint(f);
    return (unsigned short)((u + 0x7FFFu + ((u >> 16) & 1u)) >> 16);
}
__device__ __forceinline__ float b2f(unsigned short u) {
    return __uint_as_float(((unsigned int)u) << 16);
}
__device__ __forceinline__ void ld4(const float* __restrict__ p, float* o) {
    float4 v = *(const float4*)p;
    o[0] = v.x; o[1] = v.y; o[2] = v.z; o[3] = v.w;
}

// async global->LDS, 16B per lane; LDS dest = wave-uniform base + lane*16
__device__ __forceinline__ void gload_lds16(const unsigned short* g, unsigned short* l) {
    __builtin_amdgcn_global_load_lds(
        (const __attribute__((address_space(1))) unsigned int*)g,
        (__attribute__((address_space(3))) unsigned int*)l, 16, 0, 0);
}

// ==================== one-shot prep ====================
struct PrepArgs {
    const float* att[6]; const float* wf[6]; float* v[6];
    const float* csrc[6]; unsigned short* cdst[6];
    int* zptr; int zn4;
};

__global__ void prep_kernel(PrepArgs a)
{
    int b = blockIdx.x, t = threadIdx.x;
    if (b < 68) {
        int f, cb;
        if (b < 2)       { f = 0; cb = b; }
        else if (b < 4)  { f = 1; cb = b - 2; }
        else if (b < 20) { f = 2; cb = b - 4; }
        else if (b < 36) { f = 3; cb = b - 20; }
        else if (b < 52) { f = 4; cb = b - 36; }
        else             { f = 5; cb = b - 52; }
        int din = (f < 2) ? 128 : 1024;
        int idx = cb * 256 + t;
        int h = idx / din, k = idx - h * din;
        const float* ar = a.att[f] + h * 256;
        const float* wr = a.wf[f] + (size_t)(h * 256) * din + k;
        float acc = 0.f;
        for (int j = 0; j < 256; ++j) acc += ar[j] * wr[(size_t)j * din];
        a.v[f][idx] = acc;
    } else if (b < 124) {
        int c = b - 68, j, ob;
        if (c < 2)       { j = 0; ob = c; }
        else if (c < 4)  { j = 1; ob = c - 2; }
        else if (c < 20) { j = 2; ob = c - 4; }
        else if (c < 36) { j = 3; ob = c - 20; }
        else if (c < 40) { j = 4; ob = c - 36; }
        else             { j = 5; ob = c - 40; }
        long base = (long)ob * 65536;
        if (j < 5) {
            const float* src = a.csrc[j];
            unsigned short* dst = a.cdst[j];
            for (int it = 0; it < 64; ++it) {
                long e = base + (long)(it * 256 + t) * 4;
                float4 v = *(const float4*)(src + e);
                ushort4 u;
                u.x = f2b(v.x); u.y = f2b(v.y); u.z = f2b(v.z); u.w = f2b(v.w);
                *(ushort4*)(dst + e) = u;
            }
        } else {  // w3 repack: wp[row*4096 + h*1024 + k] = 0.25*w[(h*256+row)*1024+k]
            const float* src = a.csrc[5];
            unsigned short* dst = a.cdst[5];
            for (int it = 0; it < 64; ++it) {
                long e = base + (long)(it * 256 + t) * 4;
                int row = (int)(e >> 12);
                int hk = (int)(e & 4095);
                int h = hk >> 10, k = hk & 1023;
                float4 v = *(const float4*)(src + ((size_t)(h * 256 + row) << 10) + k);
                ushort4 u;
                u.x = f2b(0.25f * v.x); u.y = f2b(0.25f * v.y);
                u.z = f2b(0.25f * v.z); u.w = f2b(0.25f * v.w);
                *(ushort4*)(dst + e) = u;
            }
        }
    } else {
        int i = (b - 124) * 256 + t;
        if (i < a.zn4) ((int4*)a.zptr)[i] = make_int4(0, 0, 0, 0);
    }
}

// ==================== CSR build for ALL layers (input-only) ====================
struct CsrArgs {
    const int* edst[3]; const int* esrc[3];
    int* counts[3]; int* offsets[3]; int* cursor[3]; int* slist[3];
    int sizes[3];
};

__global__ void count_all(CsrArgs a)
{
    int id = blockIdx.x * 256 + threadIdx.x;
    int L, e;
    if (id < E1)           { L = 0; e = id; }
    else if (id < E1 + E2) { L = 1; e = id - E1; }
    else if (id < E1 + E2 + E3) { L = 2; e = id - E1 - E2; }
    else return;
    atomicAdd(&a.counts[L][a.edst[L][e]], 1);
}

__global__ void scan_all(CsrArgs a)
{
    __shared__ int lds[1024];
    int L = blockIdx.x;
    int size = a.sizes[L];
    const int* counts = a.counts[L];
    int* offsets = a.offsets[L];
    int* cursor = a.cursor[L];
    int t = threadIdx.x;
    int chunk = (size + 1023) >> 10;
    int begin = t * chunk;
    int end = begin + chunk; if (end > size) end = size;
    if (begin > size) begin = size;
    int s = 0;
    if ((chunk & 3) == 0) {
        for (int i = begin; i < end; i += 4) {
            int4 v = *(const int4*)(counts + i);
            s += v.x + v.y + v.z + v.w;
        }
    } else {
        for (int i = begin; i < end; ++i) s += counts[i];
    }
    lds[t] = s;
    __syncthreads();
    for (int d = 1; d < 1024; d <<= 1) {
        int v = (t >= d) ? lds[t - d] : 0;
        __syncthreads();
        lds[t] += v;
        __syncthreads();
    }
    int base = (t > 0) ? lds[t - 1] : 0;
    for (int i = begin; i < end; ++i) {
        offsets[i] = base; cursor[i] = base;
        base += counts[i];
    }
    if (t == 1023) offsets[size] = lds[1023];
}

__global__ void scatter_all(CsrArgs a)
{
    int id = blockIdx.x * 256 + threadIdx.x;
    int L, e;
    if (id < E1)           { L = 0; e = id; }
    else if (id < E1 + E2) { L = 1; e = id - E1; }
    else if (id < E1 + E2 + E3) { L = 2; e = id - E1 - E2; }
    else return;
    int p = atomicAdd(&a.cursor[L][a.edst[L][e]], 1);
    a.slist[L][p] = a.esrc[L][e];
}

// ==================== L1: fused f32->bf16 conv + al_src + al_dst ====================
// unroll-2: each 32-lane half processes 2 consecutive nodes per iteration
__global__ void al128f_kernel(const float* __restrict__ x, const float* __restrict__ vs,
                              const float* __restrict__ vd, unsigned short* __restrict__ xb,
                              float* __restrict__ als, float* __restrict__ ald, int n, int ndst)
{
    int lane = threadIdx.x & 63;
    int wave = (blockIdx.x * 256 + threadIdx.x) >> 6;
    int nw = (gridDim.x * 256) >> 6;
    int j32 = lane & 31, half = lane >> 5;
    float vsr[4][4], vdr[4][4];
    #pragma unroll
    for (int h = 0; h < 4; ++h) {
        ld4(vs + h * 128 + j32 * 4, vsr[h]);
        ld4(vd + h * 128 + j32 * 4, vdr[h]);
    }
    for (long base = (long)wave * 4 + half * 2; base < n; base += (long)nw * 4) {
        float4 xv0 = *(const float4*)(x + base * 128 + j32 * 4);
        float4 xv1 = *(const float4*)(x + (base + 1) * 128 + j32 * 4);
        ushort4 u0, u1;
        u0.x = f2b(xv0.x); u0.y = f2b(xv0.y); u0.z = f2b(xv0.z); u0.w = f2b(xv0.w);
        u1.x = f2b(xv1.x); u1.y = f2b(xv1.y); u1.z = f2b(xv1.z); u1.w = f2b(xv1.w);
        *(ushort4*)(xb + base * 128 + j32 * 4) = u0;
        *(ushort4*)(xb + (base + 1) * 128 + j32 * 4) = u1;
        float f0[4] = { xv0.x, xv0.y, xv0.z, xv0.w };
        float f1[4] = { xv1.x, xv1.y, xv1.z, xv1.w };
        float a0[4], a1[4], b0[4], b1[4];
        bool isd = base < ndst;
        #pragma unroll
        for (int h = 0; h < 4; ++h) {
            a0[h] = f0[0]*vsr[h][0] + f0[1]*vsr[h][1] + f0[2]*vsr[h][2] + f0[3]*vsr[h][3];
            a1[h] = f1[0]*vsr[h][0] + f1[1]*vsr[h][1] + f1[2]*vsr[h][2] + f1[3]*vsr[h][3];
        }
        if (isd) {
            #pragma unroll
            for (int h = 0; h < 4; ++h) {
                b0[h] = f0[0]*vdr[h][0] + f0[1]*vdr[h][1] + f0[2]*vdr[h][2] + f0[3]*vdr[h][3];
                b1[h] = f1[0]*vdr[h][0] + f1[1]*vdr[h][1] + f1[2]*vdr[h][2] + f1[3]*vdr[h][3];
            }
        }
        #pragma unroll
        for (int off = 16; off > 0; off >>= 1) {
            #pragma unroll
            for (int h = 0; h < 4; ++h) {
                a0[h] += __shfl_xor(a0[h], off);
                a1[h] += __shfl_xor(a1[h], off);
            }
            if (isd)
                #pragma unroll
                for (int h = 0; h < 4; ++h) {
                    b0[h] += __shfl_xor(b0[h], off);
                    b1[h] += __shfl_xor(b1[h], off);
                }
        }
        if (j32 == 0) {
            *(float4*)(als + base * 4) = make_float4(a0[0], a0[1], a0[2], a0[3]);
            *(float4*)(als + (base + 1) * 4) = make_float4(a1[0], a1[1], a1[2], a1[3]);
            if (isd) {
                *(float4*)(ald + base * 4) = make_float4(b0[0], b0[1], b0[2], b0[3]);
                *(float4*)(ald + (base + 1) * 4) = make_float4(b1[0], b1[1], b1[2], b1[3]);
            }
        }
    }
}

// ==================== L2/L3: al src+dst in ONE launch (grid split) ====================
__global__ void al1024d_kernel(const unsigned short* __restrict__ xb,
                               const float* __restrict__ vs, const float* __restrict__ vd,
                               float* __restrict__ als, float* __restrict__ ald,
                               int nsrc, int ndst, int bsrc)
{
    bool isdst = (int)blockIdx.x >= bsrc;
    const float* v = isdst ? vd : vs;
    float* al = isdst ? ald : als;
    int n = isdst ? ndst : nsrc;
    int b0 = isdst ? blockIdx.x - bsrc : blockIdx.x;
    int nb = isdst ? gridDim.x - bsrc : bsrc;
    int lane = threadIdx.x & 63;
    int wave = (b0 * 256 + threadIdx.x) >> 6;
    int nwaves = (nb * 256) >> 6;
    float vr[4][16];
    #pragma unroll
    for (int h = 0; h < 4; ++h)
        #pragma unroll
        for (int it = 0; it < 2; ++it) {
            ld4(v + h * 1024 + it * 512 + lane * 8,     &vr[h][it * 8]);
            ld4(v + h * 1024 + it * 512 + lane * 8 + 4, &vr[h][it * 8 + 4]);
        }
    for (long node = wave; node < n; node += nwaves) {
        const unsigned short* xr = xb + node * 1024;
        float a[4] = {0.f, 0.f, 0.f, 0.f};
        #pragma unroll
        for (int it = 0; it < 2; ++it) {
            short8 u = *(const short8*)(xr + it * 512 + lane * 8);
            #pragma unroll
            for (int j = 0; j < 8; ++j) {
                float xv = b2f((unsigned short)u[j]);
                #pragma unroll
                for (int h = 0; h < 4; ++h) a[h] += xv * vr[h][it * 8 + j];
            }
        }
        #pragma unroll
        for (int off = 32; off > 0; off >>= 1)
            #pragma unroll
            for (int h = 0; h < 4; ++h) a[h] += __shfl_xor(a[h], off);
        if (lane == 0) *(float4*)(al + node * 4) = make_float4(a[0], a[1], a[2], a[3]);
    }
}

// ==================== wave-parallel softmax stats + per-slot alpha ====================
__global__ void mdnw_kernel(const float* __restrict__ als, const float* __restrict__ ald,
                            const int* __restrict__ offsets, const int* __restrict__ slist,
                            int size, float* __restrict__ aself, float* __restrict__ walpha)
{
    int d = blockIdx.x * 4 + (threadIdx.x >> 6);
    if (d >= size) return;
    int lane = threadIdx.x & 63;
    float ad[4], sl[4], q[4];
    ld4(ald + 4 * (size_t)d, ad);
    ld4(als + 4 * (size_t)d, q);
    #pragma unroll
    for (int h = 0; h < 4; ++h) sl[h] = lrelu(q[h] + ad[h]);
    int beg = offsets[d], deg = offsets[d + 1] - beg;
    float m[4] = { sl[0], sl[1], sl[2], sl[3] };
    for (int p = lane; p < deg; p += 64) {
        int s = slist[beg + p];
        ld4(als + 4 * (size_t)s, q);
        #pragma unroll
        for (int h = 0; h < 4; ++h) m[h] = fmaxf(m[h], lrelu(q[h] + ad[h]));
    }
    #pragma unroll
    for (int off = 32; off > 0; off >>= 1)
        #pragma unroll
        for (int h = 0; h < 4; ++h) m[h] = fmaxf(m[h], __shfl_xor(m[h], off));
    float dn[4] = {0.f, 0.f, 0.f, 0.f};
    for (int p = lane; p < deg; p += 64) {
        int s = slist[beg + p];
        ld4(als + 4 * (size_t)s, q);
        #pragma unroll
        for (int h = 0; h < 4; ++h) dn[h] += expf(lrelu(q[h] + ad[h]) - m[h]);
    }
    #pragma unroll
    for (int off = 32; off > 0; off >>= 1)
        #pragma unroll
        for (int h = 0; h < 4; ++h) dn[h] += __shfl_xor(dn[h], off);
    float r[4];
    #pragma unroll
    for (int h = 0; h < 4; ++h)
        r[h] = 1.f / (dn[h] + expf(sl[h] - m[h]) + 1e-16f);
    if (lane == 0) {
        float4 w;
        w.x = expf(sl[0] - m[0]) * r[0];
        w.y = expf(sl[1] - m[1]) * r[1];
        w.z = expf(sl[2] - m[2]) * r[2];
        w.w = expf(sl[3] - m[3]) * r[3];
        *(float4*)(aself + 4 * (size_t)d) = w;
    }
    for (int p = lane; p < deg; p += 64) {
        int s = slist[beg + p];
        ld4(als + 4 * (size_t)s, q);
        float4 w;
        w.x = expf(lrelu(q[0] + ad[0]) - m[0]) * r[0];
        w.y = expf(lrelu(q[1] + ad[1]) - m[1]) * r[1];
        w.z = expf(lrelu(q[2] + ad[2]) - m[2]) * r[2];
        w.w = expf(lrelu(q[3] + ad[3]) - m[3]) * r[3];
        *(float4*)(walpha + 4 * (size_t)(beg + p)) = w;
    }
}

// ==================== aggregation (slot-indexed alpha, direct src ids) ====================
__global__ void agg128_kernel(const unsigned short* __restrict__ xb, const float* __restrict__ walpha,
                              const float* __restrict__ aself,
                              const int* __restrict__ offsets, const int* __restrict__ slist,
                              int size, unsigned short* __restrict__ aggb)
{
    int d = blockIdx.x * 4 + (threadIdx.x >> 6);
    if (d >= size) return;
    int lane = threadIdx.x & 63;
    int beg = offsets[d], end = offsets[d + 1];
    float w[4], acc[4][2];
    ld4(aself + 4 * (size_t)d, w);
    {
        unsigned int u = *(const unsigned int*)(xb + (size_t)d * 128 + lane * 2);
        float x0 = b2f((unsigned short)(u & 0xFFFF)), x1 = b2f((unsigned short)(u >> 16));
        #pragma unroll
        for (int h = 0; h < 4; ++h) { acc[h][0] = w[h] * x0; acc[h][1] = w[h] * x1; }
    }
    for (int p = beg; p < end; ++p) {
        int s = slist[p];
        ld4(walpha + 4 * (size_t)p, w);
        unsigned int u = *(const unsigned int*)(xb + (size_t)s * 128 + lane * 2);
        float x0 = b2f((unsigned short)(u & 0xFFFF)), x1 = b2f((unsigned short)(u >> 16));
        #pragma unroll
        for (int h = 0; h < 4; ++h) { acc[h][0] += w[h] * x0; acc[h][1] += w[h] * x1; }
    }
    unsigned int* og = (unsigned int*)(aggb + (size_t)d * 512);
    #pragma unroll
    for (int h = 0; h < 4; ++h)
        og[h * 64 + lane] = (unsigned int)f2b(acc[h][0]) | ((unsigned int)f2b(acc[h][1]) << 16);
}

__global__ void agg1024_kernel(const unsigned short* __restrict__ xb, const float* __restrict__ walpha,
                               const float* __restrict__ aself,
                               const int* __restrict__ offsets, const int* __restrict__ slist,
                               unsigned short* __restrict__ aggb)
{
    int d = blockIdx.x, t = threadIdx.x;
    int beg = offsets[d], end = offsets[d + 1];
    float w[4], acc[4][4];
    ld4(aself + 4 * (size_t)d, w);
    {
        ushort4 u = *(const ushort4*)(xb + (size_t)d * 1024 + t * 4);
        float xv[4] = { b2f(u.x), b2f(u.y), b2f(u.z), b2f(u.w) };
        #pragma unroll
        for (int h = 0; h < 4; ++h)
            #pragma unroll
            for (int j = 0; j < 4; ++j) acc[h][j] = w[h] * xv[j];
    }
    for (int p = beg; p < end; ++p) {
        int s = slist[p];
        ld4(walpha + 4 * (size_t)p, w);
        ushort4 u = *(const ushort4*)(xb + (size_t)s * 1024 + t * 4);
        float xv[4] = { b2f(u.x), b2f(u.y), b2f(u.z), b2f(u.w) };
        #pragma unroll
        for (int h = 0; h < 4; ++h)
            #pragma unroll
            for (int j = 0; j < 4; ++j) acc[h][j] += w[h] * xv[j];
    }
    unsigned short* og = aggb + (size_t)d * 4096;
    #pragma unroll
    for (int h = 0; h < 4; ++h) {
        ushort4 u;
        u.x = f2b(acc[h][0]); u.y = f2b(acc[h][1]);
        u.z = f2b(acc[h][2]); u.w = f2b(acc[h][3]);
        *(ushort4*)(og + h * 1024 + t * 4) = u;
    }
}

// ==================== fused dual-phase bf16 MFMA GEMM + BN stats, BK=32 (L1) ====================
#define SWZ(r, c) ((((c) ^ (((r) >> 1) & 3)) << 3))

template<int BM, int BN>
__global__ __launch_bounds__(256) void gemm2_kernel(
    const unsigned short* __restrict__ A1, int lda1, const unsigned short* __restrict__ W1, int K1,
    const unsigned short* __restrict__ A2, int lda2, const unsigned short* __restrict__ W2, int K2,
    int hs2, int cph2,
    unsigned short* __restrict__ C, int N,
    float* __restrict__ bnsum, float* __restrict__ bnsq)
{
    constexpr int WM = BM / 2, WN = BN / 2;
    constexpr int TM = WM / 16, TN = WN / 16;
    constexpr int APASS = (BM * 4) / 256, BPASS = (BN * 4) / 256;
    __shared__ __align__(16) unsigned short As[BM * 32];
    __shared__ __align__(16) unsigned short Bs[BN * 32];
    __shared__ float sbn[2 * BN];
    int tid = threadIdx.x;
    int gx = gridDim.x;
    int nwg = gx * gridDim.y;
    int bid = blockIdx.y * gx + blockIdx.x;
    int cpx = nwg >> 3;
    int swz = (bid & 7) * cpx + (bid >> 3);
    int n0 = (swz % gx) * BN, m0 = (swz / gx) * BM;
    int l = tid & 63, l16 = l & 15, kq = l >> 4;
    int wid = tid >> 6, wr = wid >> 1, wc = wid & 1;

    f32x4 acc[TM][TN];
    #pragma unroll
    for (int mi = 0; mi < TM; ++mi)
        #pragma unroll
        for (int ni = 0; ni < TN; ++ni) acc[mi][ni] = (f32x4){0.f, 0.f, 0.f, 0.f};

    #pragma unroll
    for (int ph = 0; ph < 2; ++ph) {
        const unsigned short* Ap = ph ? A2 + (size_t)m0 * lda2 + (cph2 ? (size_t)(n0 / cph2) * hs2 : 0)
                                      : A1 + (size_t)m0 * lda1;
        int lda = ph ? lda2 : lda1;
        const unsigned short* Wp = ph ? W2 + (size_t)n0 * K2 : W1 + (size_t)n0 * K1;
        int ldw = ph ? K2 : K1;
        int K = ph ? K2 : K1;
        for (int k0 = 0; k0 < K; k0 += 32) {
            #pragma unroll
            for (int ps = 0; ps < APASS; ++ps) {
                int sbase = ps * 256 + wid * 64;
                int s = sbase + l;
                int r = s >> 2, cc = s & 3;
                gload_lds16(Ap + (size_t)r * lda + k0 + ((cc ^ ((r >> 1) & 3)) << 3),
                            &As[(size_t)sbase * 8]);
            }
            #pragma unroll
            for (int ps = 0; ps < BPASS; ++ps) {
                int sbase = ps * 256 + wid * 64;
                int s = sbase + l;
                int r = s >> 2, cc = s & 3;
                gload_lds16(Wp + (size_t)r * ldw + k0 + ((cc ^ ((r >> 1) & 3)) << 3),
                            &Bs[(size_t)sbase * 8]);
            }
            __syncthreads();
            short8 af[TM], bfr[TN];
            #pragma unroll
            for (int mi = 0; mi < TM; ++mi) {
                int r = wr * WM + mi * 16 + l16;
                af[mi] = *(const short8*)&As[r * 32 + SWZ(r, kq)];
            }
            #pragma unroll
            for (int ni = 0; ni < TN; ++ni) {
                int r = wc * WN + ni * 16 + l16;
                bfr[ni] = *(const short8*)&Bs[r * 32 + SWZ(r, kq)];
            }
            #pragma unroll
            for (int mi = 0; mi < TM; ++mi)
                #pragma unroll
                for (int ni = 0; ni < TN; ++ni)
                    acc[mi][ni] = __builtin_amdgcn_mfma_f32_16x16x32_bf16(
                        af[mi], bfr[ni], acc[mi][ni], 0, 0, 0);
            __syncthreads();
        }
    }

    if (tid < 2 * BN) sbn[tid] = 0.f;
    __syncthreads();

    #pragma unroll
    for (int ni = 0; ni < TN; ++ni) {
        int col = wc * WN + ni * 16 + l16;
        float s = 0.f, q = 0.f;
        #pragma unroll
        for (int mi = 0; mi < TM; ++mi) {
            int rowb = wr * WM + mi * 16 + (kq << 2);
            #pragma unroll
            for (int r = 0; r < 4; ++r) {
                float v = acc[mi][ni][r];
                C[(size_t)(m0 + rowb + r) * N + n0 + col] = f2b(v);
                s += v; q += v * v;
            }
        }
        atomicAdd(&sbn[col * 2 + 0], s);
        atomicAdd(&sbn[col * 2 + 1], q);
    }
    __syncthreads();
    if (tid < BN) {
        atomicAdd(&bnsum[n0 + tid], sbn[tid * 2 + 0]);
        atomicAdd(&bnsq[n0 + tid], sbn[tid * 2 + 1]);
    }
}

// ==================== BK=64 variant (L2 GEMM; K % 64 == 0) ====================
// Row = 64 shorts = 8×16B chunks. LDS slot r*8+c' holds global chunk c'^(r&7):
// store via chunk-permuted source, read with the same XOR (involution).
template<int BM, int BN>
__global__ __launch_bounds__(256) void gemm2k64_kernel(
    const unsigned short* __restrict__ A1, int lda1, const unsigned short* __restrict__ W1, int K1,
    const unsigned short* __restrict__ A2, int lda2, const unsigned short* __restrict__ W2, int K2,
    int hs2, int cph2,
    unsigned short* __restrict__ C, int N,
    float* __restrict__ bnsum, float* __restrict__ bnsq)
{
    constexpr int WM = BM / 2, WN = BN / 2;
    constexpr int TM = WM / 16, TN = WN / 16;
    constexpr int APASS = (BM * 8) / 256, BPASS = (BN * 8) / 256;
    __shared__ __align__(16) unsigned short As[BM * 64];
    __shared__ __align__(16) unsigned short Bs[BN * 64];
    __shared__ float sbn[2 * BN];
    int tid = threadIdx.x;
    int gx = gridDim.x;
    int nwg = gx * gridDim.y;
    int bid = blockIdx.y * gx + blockIdx.x;
    int cpx = nwg >> 3;
    int swz = (bid & 7) * cpx + (bid >> 3);
    int n0 = (swz % gx) * BN, m0 = (swz / gx) * BM;
    int l = tid & 63, l16 = l & 15, kq = l >> 4;
    int wid = tid >> 6, wr = wid >> 1, wc = wid & 1;

    f32x4 acc[TM][TN];
    #pragma unroll
    for (int mi = 0; mi < TM; ++mi)
        #pragma unroll
        for (int ni = 0; ni < TN; ++ni) acc[mi][ni] = (f32x4){0.f, 0.f, 0.f, 0.f};

    #pragma unroll
    for (int ph = 0; ph < 2; ++ph) {
        const unsigned short* Ap = ph ? A2 + (size_t)m0 * lda2 + (cph2 ? (size_t)(n0 / cph2) * hs2 : 0)
                                      : A1 + (size_t)m0 * lda1;
        int lda = ph ? lda2 : lda1;
        const unsigned short* Wp = ph ? W2 + (size_t)n0 * K2 : W1 + (size_t)n0 * K1;
        int ldw = ph ? K2 : K1;
        int K = ph ? K2 : K1;
        for (int k0 = 0; k0 < K; k0 += 64) {
            #pragma unroll
            for (int ps = 0; ps < APASS; ++ps) {
                int sbase = ps * 256 + wid * 64;
                int s = sbase + l;
                int r = s >> 3, cc = s & 7;
                gload_lds16(Ap + (size_t)r * lda + k0 + ((cc ^ (r & 7)) << 3),
                            &As[(size_t)sbase * 8]);
            }
            #pragma unroll
            for (int ps = 0; ps < BPASS; ++ps) {
                int sbase = ps * 256 + wid * 64;
                int s = sbase + l;
                int r = s >> 3, cc = s & 7;
                gload_lds16(Wp + (size_t)r * ldw + k0 + ((cc ^ (r & 7)) << 3),
                            &Bs[(size_t)sbase * 8]);
            }
            __syncthreads();
            #pragma unroll
            for (int kk = 0; kk < 2; ++kk) {
                short8 af[TM], bfr[TN];
                #pragma unroll
                for (int mi = 0; mi < TM; ++mi) {
                    int r = wr * WM + mi * 16 + l16;
                    af[mi] = *(const short8*)&As[r * 64 + (((kk * 4 + kq) ^ (r & 7)) << 3)];
                }
                #pragma unroll
                for (int ni = 0; ni < TN; ++ni) {
                    int r = wc * WN + ni * 16 + l16;
                    bfr[ni] = *(const short8*)&Bs[r * 64 + (((kk * 4 + kq) ^ (r & 7)) << 3)];
                }
                #pragma unroll
                for (int mi = 0; mi < TM; ++mi)
                    #pragma unroll
                    for (int ni = 0; ni < TN; ++ni)
                        acc[mi][ni] = __builtin_amdgcn_mfma_f32_16x16x32_bf16(
                            af[mi], bfr[ni], acc[mi][ni], 0, 0, 0);
            }
            __syncthreads();
        }
    }

    if (tid < 2 * BN) sbn[tid] = 0.f;
    __syncthreads();

    #pragma unroll
    for (int ni = 0; ni < TN; ++ni) {
        int col = wc * WN + ni * 16 + l16;
        float s = 0.f, q = 0.f;
        #pragma unroll
        for (int mi = 0; mi < TM; ++mi) {
            int rowb = wr * WM + mi * 16 + (kq << 2);
            #pragma unroll
            for (int r = 0; r < 4; ++r) {
                float v = acc[mi][ni][r];
                C[(size_t)(m0 + rowb + r) * N + n0 + col] = f2b(v);
                s += v; q += v * v;
            }
        }
        atomicAdd(&sbn[col * 2 + 0], s);
        atomicAdd(&sbn[col * 2 + 1], q);
    }
    __syncthreads();
    if (tid < BN) {
        atomicAdd(&bnsum[n0 + tid], sbn[tid * 2 + 0]);
        atomicAdd(&bnsq[n0 + tid], sbn[tid * 2 + 1]);
    }
}

// ==================== L3: split-K GEMM -> Cpart[z][512][256] (deterministic) ====================
__global__ __launch_bounds__(256) void gemm3_splitk(
    const unsigned short* __restrict__ A1, const unsigned short* __restrict__ W1,
    const unsigned short* __restrict__ A2, const unsigned short* __restrict__ W2,
    float* __restrict__ Cpart)
{
    constexpr int BM = 64, BN = 64, WM = 32, WN = 32, TM = 2, TN = 2;
    __shared__ __align__(16) unsigned short As[BM * 32];
    __shared__ __align__(16) unsigned short Bs[BN * 32];
    int tid = threadIdx.x;
    int n0 = blockIdx.x * BN, m0 = blockIdx.y * BM;
    int z = blockIdx.z;
    int ph = (z >= 2);
    int ks = ph ? (z - 2) * 512 : z * 512;
    const unsigned short* Ap = ph ? A2 + (size_t)m0 * 4096 : A1 + (size_t)m0 * 1024;
    const unsigned short* Wp = ph ? W2 + (size_t)n0 * 4096 : W1 + (size_t)n0 * 1024;
    int lda = ph ? 4096 : 1024;
    int l = tid & 63, l16 = l & 15, kq = l >> 4;
    int wid = tid >> 6, wr = wid >> 1, wc = wid & 1;

    f32x4 acc[TM][TN];
    #pragma unroll
    for (int mi = 0; mi < TM; ++mi)
        #pragma unroll
        for (int ni = 0; ni < TN; ++ni) acc[mi][ni] = (f32x4){0.f, 0.f, 0.f, 0.f};

    for (int k0 = ks; k0 < ks + 512; k0 += 32) {
        {
            int sbase = wid * 64;
            int s = sbase + l;
            int r = s >> 2, cc = s & 3;
            gload_lds16(Ap + (size_t)r * lda + k0 + ((cc ^ ((r >> 1) & 3)) << 3),
                        &As[(size_t)sbase * 8]);
            gload_lds16(Wp + (size_t)r * lda + k0 + ((cc ^ ((r >> 1) & 3)) << 3),
                        &Bs[(size_t)sbase * 8]);
        }
        __syncthreads();
        short8 af[TM], bfr[TN];
        #pragma unroll
        for (int mi = 0; mi < TM; ++mi) {
            int r = wr * WM + mi * 16 + l16;
            af[mi] = *(const short8*)&As[r * 32 + SWZ(r, kq)];
        }
        #pragma unroll
        for (int ni = 0; ni < TN; ++ni) {
            int r = wc * WN + ni * 16 + l16;
            bfr[ni] = *(const short8*)&Bs[r * 32 + SWZ(r, kq)];
        }
        #pragma unroll
        for (int mi = 0; mi < TM; ++mi)
            #pragma unroll
            for (int ni = 0; ni < TN; ++ni)
                acc[mi][ni] = __builtin_amdgcn_mfma_f32_16x16x32_bf16(
                    af[mi], bfr[ni], acc[mi][ni], 0, 0, 0);
        __syncthreads();
    }

    float* Cz = Cpart + (size_t)z * S3 * 256;
    #pragma unroll
    for (int ni = 0; ni < TN; ++ni) {
        int col = wc * WN + ni * 16 + l16;
        #pragma unroll
        for (int mi = 0; mi < TM; ++mi) {
            int rowb = wr * WM + mi * 16 + (kq << 2);
            #pragma unroll
            for (int r = 0; r < 4; ++r)
                Cz[(size_t)(m0 + rowb + r) * 256 + n0 + col] = acc[mi][ni][r];
        }
    }
}

// reduce Cpart over z -> hb32, accumulate BN column stats
__global__ void bnstat3_kernel(const float* __restrict__ Cpart, float* __restrict__ hb32,
                               float* __restrict__ bnsum, float* __restrict__ bnsq)
{
    int c = threadIdx.x;
    int r0 = blockIdx.x * 64;
    float s = 0.f, q = 0.f;
    for (int r = r0; r < r0 + 64; ++r) {
        float v = 0.f;
        #pragma unroll
        for (int z = 0; z < 10; ++z)
            v += Cpart[((size_t)z * S3 + r) * 256 + c];
        hb32[(size_t)r * 256 + c] = v;
        s += v; q += v * v;
    }
    atomicAdd(&bnsum[c], s);
    atomicAdd(&bnsq[c], q);
}

// ==================== BN finalize fused into apply + ELU (8 elems/thread) ====================
__global__ void norm_elu_bb(const unsigned short* __restrict__ h,
                            const float* __restrict__ sum, const float* __restrict__ sq,
                            const float* __restrict__ gamma, const float* __restrict__ beta,
                            unsigned short* __restrict__ out, int N, float invM, long total)
{
    long i0 = ((long)blockIdx.x * 256 + threadIdx.x) * 8;
    if (i0 >= total) return;
    #pragma unroll
    for (int g = 0; g < 2; ++g) {
        long i = i0 + g * 4;
        int c = (int)(i % N);
        float4 sm = *(const float4*)(sum + c);
        float4 qq = *(const float4*)(sq + c);
        float4 gm = *(const float4*)(gamma + c);
        float4 bt = *(const float4*)(beta + c);
        float mu0 = sm.x * invM, mu1 = sm.y * invM, mu2 = sm.z * invM, mu3 = sm.w * invM;
        float sc0 = gm.x * rsqrtf(qq.x * invM - mu0 * mu0 + BN_EPS);
        float sc1 = gm.y * rsqrtf(qq.y * invM - mu1 * mu1 + BN_EPS);
        float sc2 = gm.z * rsqrtf(qq.z * invM - mu2 * mu2 + BN_EPS);
        float sc3 = gm.w * rsqrtf(qq.w * invM - mu3 * mu3 + BN_EPS);
        float sh0 = bt.x - mu0 * sc0, sh1 = bt.y - mu1 * sc1;
        float sh2 = bt.z - mu2 * sc2, sh3 = bt.w - mu3 * sc3;
        ushort4 u = *(const ushort4*)(h + i);
        float v0 = b2f(u.x) * sc0 + sh0;
        float v1 = b2f(u.y) * sc1 + sh1;
        float v2 = b2f(u.z) * sc2 + sh2;
        float v3 = b2f(u.w) * sc3 + sh3;
        v0 = v0 > 0.f ? v0 : expm1f(v0);
        v1 = v1 > 0.f ? v1 : expm1f(v1);
        v2 = v2 > 0.f ? v2 : expm1f(v2);
        v3 = v3 > 0.f ? v3 : expm1f(v3);
        ushort4 o;
        o.x = f2b(v0); o.y = f2b(v1); o.z = f2b(v2); o.w = f2b(v3);
        *(ushort4*)(out + i) = o;
    }
}

__global__ void norm_elu_ff(const float* __restrict__ h,
                            const float* __restrict__ sum, const float* __restrict__ sq,
                            const float* __restrict__ gamma, const float* __restrict__ beta,
                            float* __restrict__ out, int N, float invM, long total)
{
    long i = ((long)blockIdx.x * 256 + threadIdx.x) * 4;
    if (i >= total) return;
    int c = (int)(i % N);
    float4 sm = *(const float4*)(sum + c);
    float4 qq = *(const float4*)(sq + c);
    float4 gm = *(const float4*)(gamma + c);
    float4 bt = *(const float4*)(beta + c);
    float mu0 = sm.x * invM, mu1 = sm.y * invM, mu2 = sm.z * invM, mu3 = sm.w * invM;
    float sc0 = gm.x * rsqrtf(qq.x * invM - mu0 * mu0 + BN_EPS);
    float sc1 = gm.y * rsqrtf(qq.y * invM - mu1 * mu1 + BN_EPS);
    float sc2 = gm.z * rsqrtf(qq.z * invM - mu2 * mu2 + BN_EPS);
    float sc3 = gm.w * rsqrtf(qq.w * invM - mu3 * mu3 + BN_EPS);
    float4 hv = *(const float4*)(h + i);
    float4 o;
    o.x = hv.x * sc0 + (bt.x - mu0 * sc0);
    o.y = hv.y * sc1 + (bt.y - mu1 * sc1);
    o.z = hv.z * sc2 + (bt.z - mu2 * sc2);
    o.w = hv.w * sc3 + (bt.w - mu3 * sc3);
    o.x = o.x > 0.f ? o.x : expm1f(o.x);
    o.y = o.y > 0.f ? o.y : expm1f(o.y);
    o.z = o.z > 0.f ? o.z : expm1f(o.z);
    o.w = o.w > 0.f ? o.w : expm1f(o.w);
    *(float4*)(out + i) = o;
}

// =====================================================================
extern "C" void kernel_launch(void* const* d_in, const int* in_sizes, int n_in,
                              void* d_out, int out_size, void* d_ws, size_t ws_size,
                              hipStream_t stream)
{
    const float* x = (const float*)d_in[0];
    auto P = [&](int layer, int slot) -> const float* {
        return (const float*)d_in[1 + (layer - 1) * 9 + slot];
    };
    const int* edge_src[3] = { (const int*)d_in[28], (const int*)d_in[30], (const int*)d_in[32] };
    const int* edge_dst[3] = { (const int*)d_in[29], (const int*)d_in[31], (const int*)d_in[33] };

    // -------- workspace carve --------
    char* wsb = (char*)d_ws;
    size_t off = 0;
    auto alloc = [&](size_t bytes) -> void* {
        void* p = wsb + off;
        off = (off + bytes + 255) & ~(size_t)255;
        return p;
    };
    unsigned short* xb0   = (unsigned short*)alloc((size_t)N0 * 128 * 2);
    unsigned short* x1b   = (unsigned short*)alloc((size_t)S1 * 1024 * 2);
    unsigned short* x2b   = (unsigned short*)alloc((size_t)S2 * 1024 * 2);
    unsigned short* hb    = (unsigned short*)alloc((size_t)S1 * 1024 * 2);
    unsigned short* aggb  = (unsigned short*)alloc((size_t)S2 * 4096 * 2);
    unsigned short* wskipb[3] = {
        (unsigned short*)alloc(131072 * 2),
        (unsigned short*)alloc(1048576 * 2),
        (unsigned short*)alloc(262144 * 2) };
    unsigned short* wsrcb[3] = {
        (unsigned short*)alloc(131072 * 2),
        (unsigned short*)alloc(1048576 * 2),
        (unsigned short*)alloc(1048576 * 2) };
    float* vbuf[6];
    vbuf[0] = (float*)alloc(512 * 4);
    vbuf[1] = (float*)alloc(512 * 4);
    vbuf[2] = (float*)alloc(4096 * 4);
    vbuf[3] = (float*)alloc(4096 * 4);
    vbuf[4] = (float*)alloc(4096 * 4);
    vbuf[5] = (float*)alloc(4096 * 4);
    float* als     = (float*)alloc((size_t)N0 * 4 * 4);
    float* ald     = (float*)alloc((size_t)S1 * 4 * 4);
    float* aself   = (float*)alloc((size_t)S1 * 4 * 4);
    float* walpha  = (float*)alloc((size_t)E1 * 4 * 4);
    float* Cpart   = (float*)alloc((size_t)10 * S3 * 256 * 4);
    float* hb32    = (float*)alloc((size_t)S3 * 256 * 4);
    int* offsets3[3] = { (int*)alloc((S1 + 1) * 4), (int*)alloc((S2 + 1) * 4), (int*)alloc((S3 + 1) * 4) };
    int* cursor3 [3] = { (int*)alloc(S1 * 4), (int*)alloc(S2 * 4), (int*)alloc(S3 * 4) };
    int* slist3  [3] = { (int*)alloc(E1 * 4), (int*)alloc(E2 * 4), (int*)alloc(E3 * 4) };
    int zn = S1 + S2 + S3 + 6 * 1024;
    int* zreg = (int*)alloc((size_t)zn * 4);
    int* counts[3] = { zreg, zreg + S1, zreg + S1 + S2 };
    float* bnsum[3] = { (float*)(zreg + S1 + S2 + S3),
                        (float*)(zreg + S1 + S2 + S3 + 2048),
                        (float*)(zreg + S1 + S2 + S3 + 4096) };
    float* bnsq[3]  = { bnsum[0] + 1024, bnsum[1] + 1024, bnsum[2] + 1024 };

    // -------- one-shot prep: folds + weight bf16 + zeroing --------
    PrepArgs pa;
    for (int L = 0; L < 3; ++L) {
        pa.att[2 * L]     = P(L + 1, 2); pa.wf[2 * L]     = P(L + 1, 0); pa.v[2 * L]     = vbuf[2 * L];
        pa.att[2 * L + 1] = P(L + 1, 3); pa.wf[2 * L + 1] = P(L + 1, 1); pa.v[2 * L + 1] = vbuf[2 * L + 1];
    }
    pa.csrc[0] = P(1, 5); pa.cdst[0] = wskipb[0];
    pa.csrc[1] = P(1, 0); pa.cdst[1] = wsrcb[0];
    pa.csrc[2] = P(2, 5); pa.cdst[2] = wskipb[1];
    pa.csrc[3] = P(2, 0); pa.cdst[3] = wsrcb[1];
    pa.csrc[4] = P(3, 5); pa.cdst[4] = wskipb[2];
    pa.csrc[5] = P(3, 0); pa.cdst[5] = wsrcb[2];
    pa.zptr = zreg; pa.zn4 = zn / 4;
    prep_kernel<<<167, 256, 0, stream>>>(pa);

    // -------- CSR build for all layers --------
    CsrArgs ca;
    for (int L = 0; L < 3; ++L) {
        ca.edst[L] = edge_dst[L]; ca.esrc[L] = edge_src[L];
        ca.counts[L] = counts[L]; ca.offsets[L] = offsets3[L];
        ca.cursor[L] = cursor3[L]; ca.slist[L] = slist3[L];
    }
    ca.sizes[0] = S1; ca.sizes[1] = S2; ca.sizes[2] = S3;
    count_all<<<(E1 + E2 + E3) / 256, 256, 0, stream>>>(ca);
    scan_all<<<3, 1024, 0, stream>>>(ca);
    scatter_all<<<(E1 + E2 + E3) / 256, 256, 0, stream>>>(ca);

    // ---------------- layer 1 ----------------
    al128f_kernel<<<2048, 256, 0, stream>>>(x, vbuf[0], vbuf[1], xb0, als, ald, N0, S1);
    mdnw_kernel<<<(S1 + 3) / 4, 256, 0, stream>>>(als, ald, offsets3[0], slist3[0], S1, aself, walpha);
    agg128_kernel<<<(S1 + 3) / 4, 256, 0, stream>>>(xb0, walpha, aself, offsets3[0], slist3[0], S1, aggb);
    gemm2_kernel<128, 128><<<dim3(1024 / 128, S1 / 128), 256, 0, stream>>>(
        xb0, 128, wskipb[0], 128,
        aggb, 512, wsrcb[0], 128, 128, 256,
        hb, 1024, bnsum[0], bnsq[0]);
    norm_elu_bb<<<(int)(((long)S1 * 1024 / 8 + 255) / 256), 256, 0, stream>>>(
        hb, bnsum[0], bnsq[0], P(1, 7), P(1, 8), x1b, 1024, 1.f / S1, (long)S1 * 1024);

    // ---------------- layer 2 ----------------
    al1024d_kernel<<<576, 256, 0, stream>>>(x1b, vbuf[2], vbuf[3], als, ald, S1, S2, 512);
    mdnw_kernel<<<(S2 + 3) / 4, 256, 0, stream>>>(als, ald, offsets3[1], slist3[1], S2, aself, walpha);
    agg1024_kernel<<<S2, 256, 0, stream>>>(x1b, walpha, aself, offsets3[1], slist3[1], aggb);
    gemm2k64_kernel<64, 64><<<dim3(1024 / 64, S2 / 64), 256, 0, stream>>>(
        x1b, 1024, wskipb[1], 1024,
        aggb, 4096, wsrcb[1], 1024, 1024, 256,
        hb, 1024, bnsum[1], bnsq[1]);
    norm_elu_bb<<<(int)(((long)S2 * 1024 / 8 + 255) / 256), 256, 0, stream>>>(
        hb, bnsum[1], bnsq[1], P(2, 7), P(2, 8), x2b, 1024, 1.f / S2, (long)S2 * 1024);

    // ---------------- layer 3 ----------------
    al1024d_kernel<<<72, 256, 0, stream>>>(x2b, vbuf[4], vbuf[5], als, ald, S2, S3, 64);
    mdnw_kernel<<<(S3 + 3) / 4, 256, 0, stream>>>(als, ald, offsets3[2], slist3[2], S3, aself, walpha);
    agg1024_kernel<<<S3, 256, 0, stream>>>(x2b, walpha, aself, offsets3[2], slist3[2], aggb);
    gemm3_splitk<<<dim3(256 / 64, S3 / 64, 10), 256, 0, stream>>>(
        x2b, wskipb[2], aggb, wsrcb[2], Cpart);
    bnstat3_kernel<<<8, 256, 0, stream>>>(Cpart, hb32, bnsum[2], bnsq[2]);
    norm_elu_ff<<<(int)(((long)S3 * 256 / 4 + 255) / 256), 256, 0, stream>>>(
        hb32, bnsum[2], bnsq[2], P(3, 7), P(3, 8), (float*)d_out, 256, 1.f / S3, (long)S3 * 256);
}